// Round 8
// baseline (153.963 us; speedup 1.0000x reference)
//
#include <hip/hip_runtime.h>
#include <hip/hip_bf16.h>

#define T_LEN 1000
#define B_N 8
#define IN_CH 80
#define CONV_CH 256
#define CCEP_N 222

typedef short s8v __attribute__((ext_vector_type(8)));      // 8 bf16 (4 VGPRs)
typedef _Float16 h8v __attribute__((ext_vector_type(8)));   // 8 fp16 (4 VGPRs)
typedef float f16v __attribute__((ext_vector_type(16)));    // MFMA 32x32 acc

#define TWO_PI 6.28318530717958647692f

// ===================== prep kernel: conv1-3 weights only ======================
// [0,288): W1p [9][256][32] fp16, k = chg*32+kloc in [0,288), kappa=k/96, i=k%96
//          (i>=80 zero-padded);
// [288,384): W2p [3][256][32], k in [0,96), kappa=k>>5, iloc=k&31;
// [384,480): W3p same.
__global__ __launch_bounds__(256) void k_prep(
    const float* __restrict__ W1, const float* __restrict__ W2,
    const float* __restrict__ W3,
    _Float16* __restrict__ W1p, _Float16* __restrict__ W2p,
    _Float16* __restrict__ W3p) {
  const int bid = blockIdx.x, tid = threadIdx.x;
  if (bid < 288) {
    int e = bid * 256 + tid;                 // 73728 = 9*8192
    int kloc = e & 31, n = (e >> 5) & 255, chg = e >> 13;
    int k = chg * 32 + kloc;
    int kappa = k / 96, i = k - kappa * 96;
    W1p[e] = (i < IN_CH) ? (_Float16)W1[n * 240 + i * 3 + kappa] : (_Float16)0.f;
  } else if (bid < 384) {
    int e = (bid - 288) * 256 + tid;         // 24576 = 3*8192
    int kloc = e & 31, n = (e >> 5) & 255, chg = e >> 13;
    int k = chg * 32 + kloc;
    int kappa = k >> 5, iloc = k & 31;
    W2p[e] = (_Float16)W2[n * 96 + iloc * 3 + kappa];
  } else {
    int e = (bid - 384) * 256 + tid;
    int kloc = e & 31, n = (e >> 5) & 255, chg = e >> 13;
    int k = chg * 32 + kloc;
    int kappa = k >> 5, iloc = k & 31;
    W3p[e] = (_Float16)W3[n * 96 + iloc * 3 + kappa];
  }
}

// ===== conv1-3 FULLY FUSED as MFMA fp16 GEMMs, h1/h2 in LDS ===================
// grid (32, 8, 3). z in {0,1}: conv planes (block = 32 t x 128 ch). z == 2:
// table-prep plane (256 blocks): Wc (conv4 bf16 weights, /quef fused) +
// twiddle + window tables. No shared state between planes; consumers
// (k_conv4m, k_fft) launch later on the same stream.
// Conv: halo via overlapping M-tiles: L1 computes h1 rows t0-2..t0+33 (tiles
// at offset 0 and +4, tile-b stores only row>=28); L2 computes h2 rows
// t0-1..t0+32 (offsets 0 and +2, tile-b stores row>=30); L3 one tile.
// Rows outside [0,T) zeroed at store (reference zero-pads each layer).
// x staged fp32->fp16 in-kernel. B double-buffered per 32-k chunk (pitch 48).
#define XP2 112   // xs pitch (halves): 224B, 4-way max bank aliasing
#define HP2 144   // h1s/h2s pitch: 288B, 4-way
#define BP2 48    // Bs pitch: 96B, 4-way

__global__ __launch_bounds__(256) void k_convfused(
    const float* __restrict__ x,
    const _Float16* __restrict__ W1p, const float* __restrict__ b1,
    const _Float16* __restrict__ W2p, const float* __restrict__ b2,
    const _Float16* __restrict__ W3p, const float* __restrict__ b3,
    __hip_bfloat16* __restrict__ out,
    const float* __restrict__ W4, __hip_bfloat16* __restrict__ Wc,
    float2* __restrict__ twTab, float* __restrict__ winTab) {
  const int tid = threadIdx.x;

  if (blockIdx.z == 2) {
    // ---- table-prep plane: Wc (196608) + twiddle (1020) + window (512) ----
    int blk = blockIdx.y * 32 + blockIdx.x;        // 0..255
    for (int e = blk * 256 + tid; e < 196608 + 1532; e += 65536) {
      if (e < 196608) {
        int kloc = e & 31, n = (e >> 5) & 255, chg = e >> 13;
        int kp = chg * 32 + kloc;
        int kappa = kp >> 8, i = kp & 255;
        float v = 0.f;
        if (n < CCEP_N) {
          float invq = 1.f / (float)((n < 111) ? (111 - n) : (n - 110));
          v = W4[n * 768 + i * 3 + kappa] * invq;
        }
        Wc[e] = __float2bfloat16(v);
      } else {
        int e2 = e - 196608;
        if (e2 < 1020) {
          int Q, off;
          if (e2 < 768)       { Q = 256; off = 0; }
          else if (e2 < 960)  { Q = 64;  off = 768; }
          else if (e2 < 1008) { Q = 16;  off = 960; }
          else                { Q = 4;   off = 1008; }
          int rem = e2 - off;
          int r = rem / Q, pos = rem - r * Q;
          float ang = (TWO_PI * (float)((r + 1) * pos)) / (float)(4 * Q);
          float s, c;
          sincosf(ang, &s, &c);
          twTab[e2] = make_float2(c, s);
        } else if (e2 < 1532) {
          int n = e2 - 1020;
          winTab[n] = (0.5f - 0.5f * cosf(TWO_PI * (float)n / 512.f)) * (1.f / 1024.f);
        }
      }
    }
    return;
  }

  const int mb = blockIdx.x, b = blockIdx.y, z = blockIdx.z;
  const int t0 = mb * 32;
  const int w = tid >> 6, lane = tid & 63;
  const int lm = lane & 31, half = lane >> 5;
  const int n0loc = w * 32;                  // wave's N-tile within block's 128
  const int c = z * 128 + n0loc + lm;        // global out channel

  __shared__ _Float16 xs[38 * XP2];          // rows t0-3 .. t0+34
  __shared__ _Float16 h1s[36 * HP2];         // idx = t-(t0-2), 0..35
  __shared__ _Float16 h2s[34 * HP2];         // idx = t-(t0-1), 0..33
  __shared__ _Float16 Bs[2][128 * BP2];

  // ---- stage x (fp32 -> fp16), zero-pad t outside [0,T) and ch >= 80 ----
  for (int e = tid; e < 38 * 96; e += 256) {
    int rr = e / 96, cc = e - rr * 96;
    int t = t0 - 3 + rr;
    float v = (cc < IN_CH && t >= 0 && t < T_LEN)
                  ? x[(b * T_LEN + t) * IN_CH + cc] : 0.f;
    xs[rr * XP2 + cc] = (_Float16)v;
  }
  {
    const _Float16* src = W1p + z * 4096;    // chg 0, this block's 128 n
    for (int e = tid; e < 512; e += 256) {
      int nl = e >> 2, c4 = e & 3;
      *(uint4*)(Bs[0] + nl * BP2 + c4 * 8) = *(const uint4*)(src + nl * 32 + c4 * 8);
    }
  }
  __syncthreads();

  // ---------- layer 1: K=288 (9 chgs), M-tiles at +0 and +4 ----------
  {
    f16v a0 = {}, a1 = {};
    for (int chg = 0; chg < 9; ++chg) {
      const int p = chg & 1;
      if (chg + 1 < 9) {
        const _Float16* src = W1p + (size_t)(chg + 1) * 8192 + z * 4096;
        for (int e = tid; e < 512; e += 256) {
          int nl = e >> 2, c4 = e & 3;
          *(uint4*)(Bs[p ^ 1] + nl * BP2 + c4 * 8) = *(const uint4*)(src + nl * 32 + c4 * 8);
        }
      }
#pragma unroll
      for (int s = 0; s < 2; ++s) {
        const int c16 = chg * 2 + s;
        const int kappa = c16 / 6;
        const int icol = (c16 - kappa * 6) * 16;
        h8v bf = *(const h8v*)(Bs[p] + (n0loc + lm) * BP2 + s * 16 + half * 8);
        h8v aa0 = *(const h8v*)(xs + (lm + kappa) * XP2 + icol + half * 8);
        h8v aa1 = *(const h8v*)(xs + (lm + kappa + 4) * XP2 + icol + half * 8);
        a0 = __builtin_amdgcn_mfma_f32_32x32x16_f16(aa0, bf, a0, 0, 0, 0);
        a1 = __builtin_amdgcn_mfma_f32_32x32x16_f16(aa1, bf, a1, 0, 0, 0);
      }
      __syncthreads();
    }
    const float bv = b1[c];
#pragma unroll
    for (int reg = 0; reg < 16; ++reg) {
      int row = (reg & 3) + 8 * (reg >> 2) + 4 * half;
      {
        int t = t0 - 2 + row;                // tile a -> idx row
        float v = (t >= 0 && t < T_LEN) ? fmaxf(a0[reg] + bv, 0.f) : 0.f;
        h1s[row * HP2 + n0loc + lm] = (_Float16)v;
      }
      if (row >= 28) {                       // tile b -> idx row+4 (32..35)
        int t = t0 + 2 + row;
        float v = (t >= 0 && t < T_LEN) ? fmaxf(a1[reg] + bv, 0.f) : 0.f;
        h1s[(row + 4) * HP2 + n0loc + lm] = (_Float16)v;
      }
    }
  }
  {
    const _Float16* src = W2p + z * 4096;    // Bs[0] free after loop barrier
    for (int e = tid; e < 512; e += 256) {
      int nl = e >> 2, c4 = e & 3;
      *(uint4*)(Bs[0] + nl * BP2 + c4 * 8) = *(const uint4*)(src + nl * 32 + c4 * 8);
    }
  }
  __syncthreads();

  // ---------- layer 2: K=96 grouped (3 chgs), M-tiles at +0 and +2 ----------
  {
    f16v a0 = {}, a1 = {};
    for (int chg = 0; chg < 3; ++chg) {
      const int p = chg & 1;
      if (chg + 1 < 3) {
        const _Float16* src = W2p + (size_t)(chg + 1) * 8192 + z * 4096;
        for (int e = tid; e < 512; e += 256) {
          int nl = e >> 2, c4 = e & 3;
          *(uint4*)(Bs[p ^ 1] + nl * BP2 + c4 * 8) = *(const uint4*)(src + nl * 32 + c4 * 8);
        }
      }
#pragma unroll
      for (int s = 0; s < 2; ++s) {
        const int c16 = chg * 2 + s;
        const int kappa = c16 >> 1;
        const int icol = n0loc + (c16 & 1) * 16;   // in-group == N-tile
        h8v bf = *(const h8v*)(Bs[p] + (n0loc + lm) * BP2 + s * 16 + half * 8);
        h8v aa0 = *(const h8v*)(h1s + (lm + kappa) * HP2 + icol + half * 8);
        h8v aa1 = *(const h8v*)(h1s + (lm + kappa + 2) * HP2 + icol + half * 8);
        a0 = __builtin_amdgcn_mfma_f32_32x32x16_f16(aa0, bf, a0, 0, 0, 0);
        a1 = __builtin_amdgcn_mfma_f32_32x32x16_f16(aa1, bf, a1, 0, 0, 0);
      }
      __syncthreads();
    }
    const float bv = b2[c];
#pragma unroll
    for (int reg = 0; reg < 16; ++reg) {
      int row = (reg & 3) + 8 * (reg >> 2) + 4 * half;
      {
        int t = t0 - 1 + row;                // tile a -> idx row
        float v = (t >= 0 && t < T_LEN) ? fmaxf(a0[reg] + bv, 0.f) : 0.f;
        h2s[row * HP2 + n0loc + lm] = (_Float16)v;
      }
      if (row >= 30) {                       // tile b -> idx row+2 (32..33)
        int t = t0 + 1 + row;
        float v = (t >= 0 && t < T_LEN) ? fmaxf(a1[reg] + bv, 0.f) : 0.f;
        h2s[(row + 2) * HP2 + n0loc + lm] = (_Float16)v;
      }
    }
  }
  {
    const _Float16* src = W3p + z * 4096;
    for (int e = tid; e < 512; e += 256) {
      int nl = e >> 2, c4 = e & 3;
      *(uint4*)(Bs[0] + nl * BP2 + c4 * 8) = *(const uint4*)(src + nl * 32 + c4 * 8);
    }
  }
  __syncthreads();

  // ---------- layer 3: K=96 grouped (3 chgs), one M-tile ----------
  {
    f16v a0 = {};
    for (int chg = 0; chg < 3; ++chg) {
      const int p = chg & 1;
      if (chg + 1 < 3) {
        const _Float16* src = W3p + (size_t)(chg + 1) * 8192 + z * 4096;
        for (int e = tid; e < 512; e += 256) {
          int nl = e >> 2, c4 = e & 3;
          *(uint4*)(Bs[p ^ 1] + nl * BP2 + c4 * 8) = *(const uint4*)(src + nl * 32 + c4 * 8);
        }
      }
#pragma unroll
      for (int s = 0; s < 2; ++s) {
        const int c16 = chg * 2 + s;
        const int kappa = c16 >> 1;
        const int icol = n0loc + (c16 & 1) * 16;
        h8v bf = *(const h8v*)(Bs[p] + (n0loc + lm) * BP2 + s * 16 + half * 8);
        h8v aa = *(const h8v*)(h2s + (lm + kappa) * HP2 + icol + half * 8);
        a0 = __builtin_amdgcn_mfma_f32_32x32x16_f16(aa, bf, a0, 0, 0, 0);
      }
      __syncthreads();
    }
    const float bv = b3[c];
#pragma unroll
    for (int reg = 0; reg < 16; ++reg) {
      int row = (reg & 3) + 8 * (reg >> 2) + 4 * half;
      int t = t0 + row;
      if (t < T_LEN)
        out[(size_t)(b * T_LEN + t) * CONV_CH + c] =
            __float2bfloat16(fmaxf(a0[reg] + bv, 0.f));
    }
  }
}

// ============ conv4 as MFMA GEMM, single pass K=768: grid (32,8) ==============
// M-tile 32 (t0=mb*32), N=256 (224 used), 4 waves x 2 accs (n = w*64 + {0,32}).
// 24 double-buffered 32-k B chunks; bias (/quef fused in Wc; bias*invq here)
// applied once. P written once (7.2 MB) instead of 4 K-split partials.
#define AP4 264
#define BPITCH 40
__global__ __launch_bounds__(256) void k_conv4m(
    const __hip_bfloat16* __restrict__ h3, const __hip_bfloat16* __restrict__ Wc,
    const float* __restrict__ bias, float* __restrict__ P) {
  const int mb = blockIdx.x, b = blockIdx.y;
  const int t0 = mb * 32;
  const int tid = threadIdx.x;
  const int w = tid >> 6, lane = tid & 63;
  const int lm = lane & 31, half = lane >> 5;

  __shared__ short h3s[34 * AP4];            // rows t0-1 .. t0+32
  __shared__ short Bs[2][256 * BPITCH];

  const ushort* h3u = (const ushort*)h3;
  for (int g = tid; g < 34 * 64; g += 256) {
    int rr = g >> 6, c4 = g & 63;
    int t = t0 + rr - 1;
    uint2 v = make_uint2(0u, 0u);
    if (t >= 0 && t < T_LEN)
      v = *(const uint2*)(h3u + (b * T_LEN + t) * CONV_CH + c4 * 4);
    *(uint2*)(h3s + rr * AP4 + c4 * 4) = v;
  }

  const ushort* Wu = (const ushort*)Wc;
#pragma unroll
  for (int it = 0; it < 4; ++it) {
    int idx = (it * 256 + tid) * 8;
    uint4 v = *(const uint4*)(Wu + idx);
    int n = idx >> 5, kloc = idx & 31;
    *(uint4*)(Bs[0] + n * BPITCH + kloc) = v;
  }
  __syncthreads();

  f16v acc0 = {}, acc1 = {};

  for (int ch = 0; ch < 24; ++ch) {
    const int p = ch & 1;
    if (ch < 23) {
      const ushort* src = Wu + (size_t)(ch + 1) * 8192;
#pragma unroll
      for (int it = 0; it < 4; ++it) {
        int idx = (it * 256 + tid) * 8;
        uint4 v = *(const uint4*)(src + idx);
        int n = idx >> 5, kloc = idx & 31;
        *(uint4*)(Bs[p ^ 1] + n * BPITCH + kloc) = v;
      }
    }
#pragma unroll
    for (int s = 0; s < 2; ++s) {
      int k0 = ch * 32 + s * 16;
      int kappa = k0 >> 8, i0 = k0 & 255;
      s8v a = *(const s8v*)(h3s + (lm + kappa) * AP4 + i0 + half * 8);
      const short* bp = Bs[p] + (w * 64 + lm) * BPITCH + s * 16 + half * 8;
      s8v b0 = *(const s8v*)(bp);
      s8v b1 = *(const s8v*)(bp + 32 * BPITCH);
      acc0 = __builtin_amdgcn_mfma_f32_32x32x16_bf16(a, b0, acc0, 0, 0, 0);
      acc1 = __builtin_amdgcn_mfma_f32_32x32x16_bf16(a, b1, acc1, 0, 0, 0);
    }
    __syncthreads();
  }

#pragma unroll
  for (int nt = 0; nt < 2; ++nt) {
    int c = w * 64 + nt * 32 + lm;
    if (c >= CCEP_N) continue;
    float invq = 1.f / (float)((c < 111) ? (111 - c) : (c - 110));
    float bq = bias[c] * invq;
    const f16v* A = nt ? &acc1 : &acc0;
#pragma unroll
    for (int reg = 0; reg < 16; ++reg) {
      int row = (reg & 3) + 8 * (reg >> 2) + 4 * half;
      int t = t0 + row;
      if (t < T_LEN)
        P[(size_t)(b * T_LEN + t) * 224 + c] = (*A)[reg] + bq;
    }
  }
}

// ============================ fused FFT kernel (2 frames/block) ===============
// Frames tA=2u, tB=2u+1. Two packed forward FFTs (c + i*fr per frame); S_A, S_B
// Hermitian -> ONE inverse: Z = S_A + i*S_B, IFFT(Z) = C_A + i*C_B (both real).
// Odd rows stored directly; even-row contributions spilled to sbl/sbr; no atomics.
__device__ __forceinline__ float2 cmul(float2 a, float2 b) {
  return make_float2(fmaf(a.x, b.x, -(a.y * b.y)), fmaf(a.x, b.y, a.y * b.x));
}
__device__ __forceinline__ float2 cadd(float2 a, float2 b) { return make_float2(a.x + b.x, a.y + b.y); }
__device__ __forceinline__ float2 csub(float2 a, float2 b) { return make_float2(a.x - b.x, a.y - b.y); }

#define LIDX(i) ((i) + ((i) >> 2))

template <int Q, int OFF>
__device__ __forceinline__ void fwd_stage2(float2* __restrict__ A,
    float2* __restrict__ B, const float2* __restrict__ Tw, int j) {
  const int pos = j & (Q - 1);
  const int base = ((j - pos) << 2) + pos;
  float2 e1 = Tw[OFF + pos], e2 = Tw[OFF + Q + pos], e3 = Tw[OFF + 2 * Q + pos];
  const float2 w1 = make_float2(e1.x, -e1.y);
  const float2 w2 = make_float2(e2.x, -e2.y);
  const float2 w3 = make_float2(e3.x, -e3.y);
#pragma unroll
  for (int arr = 0; arr < 2; ++arr) {
    float2* X = arr ? B : A;
    float2 a = X[LIDX(base)], b = X[LIDX(base + Q)];
    float2 cc = X[LIDX(base + 2 * Q)], d = X[LIDX(base + 3 * Q)];
    float2 t0 = cadd(a, cc), t1 = csub(a, cc), t2 = cadd(b, d), bd = csub(b, d);
    float2 t3 = make_float2(bd.y, -bd.x);
    X[LIDX(base)]         = cadd(t0, t2);
    X[LIDX(base + Q)]     = cmul(cadd(t1, t3), w1);
    X[LIDX(base + 2 * Q)] = cmul(csub(t0, t2), w2);
    X[LIDX(base + 3 * Q)] = cmul(csub(t1, t3), w3);
  }
}

template <int Q, int OFF>
__device__ __forceinline__ void inv_stage_t(float2* __restrict__ X,
    const float2* __restrict__ Tw, int j) {
  const int pos = j & (Q - 1);
  const int base = ((j - pos) << 2) + pos;
  const float2 w1 = Tw[OFF + pos];
  const float2 w2 = Tw[OFF + Q + pos];
  const float2 w3 = Tw[OFF + 2 * Q + pos];
  float2 a = X[LIDX(base)];
  float2 b = cmul(X[LIDX(base + Q)], w1);
  float2 cc = cmul(X[LIDX(base + 2 * Q)], w2);
  float2 d = cmul(X[LIDX(base + 3 * Q)], w3);
  float2 t0 = cadd(a, cc), t1 = csub(a, cc), t2 = cadd(b, d), bd = csub(b, d);
  float2 t3 = make_float2(-bd.y, bd.x);
  X[LIDX(base)]         = cadd(t0, t2);
  X[LIDX(base + Q)]     = cadd(t1, t3);
  X[LIDX(base + 2 * Q)] = csub(t0, t2);
  X[LIDX(base + 3 * Q)] = csub(t1, t3);
}

__device__ __forceinline__ int rev4d(int v) {
  return ((v & 3) << 6) | (((v >> 2) & 3) << 4) | (((v >> 4) & 3) << 2) | ((v >> 6) & 3);
}

// grid (500, 8)
__global__ __launch_bounds__(256) void k_fft(const float* __restrict__ Pb,
    const float* __restrict__ z, const float2* __restrict__ twg,
    const float* __restrict__ wing, float* __restrict__ out,
    float* __restrict__ sbl, float* __restrict__ sbr) {
  const int u = blockIdx.x, b = blockIdx.y;
  const int tA = 2 * u, tB = tA + 1;
  const int btA = b * T_LEN + tA, btB = btA + 1;
  const int j = threadIdx.x;
  __shared__ float2 WlA[1280];
  __shared__ float2 WlB[1280];
  __shared__ float2 Tws[1020];
  for (int e = j; e < 1020; e += 256) Tws[e] = twg[e];

  const float* zb = z + b * 256000;
  float f0A = 0.f, fS, f1B = 0.f;
  {
    int zi0 = tA * 256 + j - 255;
    f0A = (zi0 >= 0) ? zb[zi0] : 0.f;
    fS = zb[tA * 256 + j + 1];
    int zi2 = tB * 256 + j + 1;
    f1B = (zi2 < 256000) ? zb[zi2] : 0.f;
  }
  float c1A = 0.f, c2A = 0.f, c1B = 0.f, c2B = 0.f;
  if (j >= 145) {
    int mA = btA * 224 + (j - 145), mB = btB * 224 + (j - 145);
    c1A = Pb[mA];
    c1B = Pb[mB];
  }
  if (j < 111) {
    int mA = btA * 224 + (j + 111), mB = btB * 224 + (j + 111);
    c2A = Pb[mA];
    c2B = Pb[mB];
  }
  __syncthreads();

  {
    float2 e1 = Tws[j], e2 = Tws[256 + j], e3 = Tws[512 + j];
    const float2 w1 = make_float2(e1.x, -e1.y);
    const float2 w2 = make_float2(e2.x, -e2.y);
    const float2 w3 = make_float2(e3.x, -e3.y);
    {
      float2 t0 = make_float2(c2A, f0A);
      float2 t1 = make_float2(-c2A, f0A);
      float2 t2 = make_float2(c1A, fS);
      float2 t3 = make_float2(fS, -c1A);
      WlA[LIDX(j)]       = cadd(t0, t2);
      WlA[LIDX(j + 256)] = cmul(cadd(t1, t3), w1);
      WlA[LIDX(j + 512)] = cmul(csub(t0, t2), w2);
      WlA[LIDX(j + 768)] = cmul(csub(t1, t3), w3);
    }
    {
      float2 t0 = make_float2(c2B, fS);
      float2 t1 = make_float2(-c2B, fS);
      float2 t2 = make_float2(c1B, f1B);
      float2 t3 = make_float2(f1B, -c1B);
      WlB[LIDX(j)]       = cadd(t0, t2);
      WlB[LIDX(j + 256)] = cmul(cadd(t1, t3), w1);
      WlB[LIDX(j + 512)] = cmul(csub(t0, t2), w2);
      WlB[LIDX(j + 768)] = cmul(csub(t1, t3), w3);
    }
  }
  __syncthreads();

  fwd_stage2<64, 768>(WlA, WlB, Tws, j);  __syncthreads();
  fwd_stage2<16, 960>(WlA, WlB, Tws, j);  __syncthreads();
  fwd_stage2<4, 1008>(WlA, WlB, Tws, j);  __syncthreads();

  const int base = 4 * j;
  float2 XA[4], XB[4];
  {
    float2 u0 = WlA[LIDX(base)], u1 = WlA[LIDX(base + 1)];
    float2 u2 = WlA[LIDX(base + 2)], u3 = WlA[LIDX(base + 3)];
    float2 t0 = cadd(u0, u2), t1 = csub(u0, u2), t2 = cadd(u1, u3), bd = csub(u1, u3);
    float2 t3 = make_float2(bd.y, -bd.x);
    XA[0] = cadd(t0, t2); XA[1] = cadd(t1, t3); XA[2] = csub(t0, t2); XA[3] = csub(t1, t3);
  }
  {
    float2 u0 = WlB[LIDX(base)], u1 = WlB[LIDX(base + 1)];
    float2 u2 = WlB[LIDX(base + 2)], u3 = WlB[LIDX(base + 3)];
    float2 t0 = cadd(u0, u2), t1 = csub(u0, u2), t2 = cadd(u1, u3), bd = csub(u1, u3);
    float2 t3 = make_float2(bd.y, -bd.x);
    XB[0] = cadd(t0, t2); XB[1] = cadd(t1, t3); XB[2] = csub(t0, t2); XB[3] = csub(t1, t3);
  }
#pragma unroll
  for (int q = 0; q < 4; ++q) { WlA[LIDX(base + q)] = XA[q]; WlB[LIDX(base + q)] = XB[q]; }
  __syncthreads();

  const int r0 = rev4d(j);
  const bool self0 = (r0 == 0);
  const int jp = self0 ? 0 : rev4d((256 - r0) & 255);
  float2 PA[4], PB[4];
#pragma unroll
  for (int q = 0; q < 4; ++q) { PA[q] = WlA[LIDX(4 * jp + q)]; PB[q] = WlB[LIDX(4 * jp + q)]; }
  float2 Z[4];
#pragma unroll
  for (int q = 0; q < 4; ++q) {
    float2 SA, SB;
    {
      float2 A = XA[q];
      float2 Bc = self0 ? PA[(4 - q) & 3] : PA[3 - q];
      float2 Y = make_float2(0.5f * (A.x + Bc.x), 0.5f * (A.y - Bc.y));
      float2 F = make_float2(0.5f * (A.y + Bc.y), -0.5f * (A.x - Bc.x));
      float mag = __expf(Y.x * 2.30258509299404568402f);
      float sy, cy;
      __sincosf(Y.y, &sy, &cy);
      float gr = mag * cy, gi = mag * sy;
      SA = make_float2(fmaf(F.x, gr, F.y * gi), fmaf(F.x, gi, -(F.y * gr)));
    }
    {
      float2 A = XB[q];
      float2 Bc = self0 ? PB[(4 - q) & 3] : PB[3 - q];
      float2 Y = make_float2(0.5f * (A.x + Bc.x), 0.5f * (A.y - Bc.y));
      float2 F = make_float2(0.5f * (A.y + Bc.y), -0.5f * (A.x - Bc.x));
      float mag = __expf(Y.x * 2.30258509299404568402f);
      float sy, cy;
      __sincosf(Y.y, &sy, &cy);
      float gr = mag * cy, gi = mag * sy;
      SB = make_float2(fmaf(F.x, gr, F.y * gi), fmaf(F.x, gi, -(F.y * gr)));
    }
    Z[q] = make_float2(SA.x - SB.y, SA.y + SB.x);   // S_A + i*S_B
  }
  __syncthreads();

  {
    float2 t0 = cadd(Z[0], Z[2]), t1 = csub(Z[0], Z[2]), t2 = cadd(Z[1], Z[3]), bd = csub(Z[1], Z[3]);
    float2 t3 = make_float2(-bd.y, bd.x);
    WlA[LIDX(base)]     = cadd(t0, t2);
    WlA[LIDX(base + 1)] = cadd(t1, t3);
    WlA[LIDX(base + 2)] = csub(t0, t2);
    WlA[LIDX(base + 3)] = csub(t1, t3);
  }
  __syncthreads();

  inv_stage_t<4, 1008>(WlA, Tws, j);  __syncthreads();
  inv_stage_t<16, 960>(WlA, Tws, j);  __syncthreads();
  inv_stage_t<64, 768>(WlA, Tws, j);  __syncthreads();

  {
    float2 w1 = Tws[j], w2 = Tws[256 + j], w3 = Tws[512 + j];
    float2 a = WlA[LIDX(j)];
    float2 bb = cmul(WlA[LIDX(j + 256)], w1);
    float2 cc = cmul(WlA[LIDX(j + 512)], w2);
    float2 d = cmul(WlA[LIDX(j + 768)], w3);
    float2 t0 = cadd(a, cc), t1 = csub(a, cc), t2 = cadd(bb, d), bd = csub(bb, d);
    float2 t3 = make_float2(-bd.y, bd.x);
    float2 Cj    = cadd(t0, t2);   // C[j]     -> corr n1 = 511-j (r-part)
    float2 Cj256 = cadd(t1, t3);   // C[j+256] -> corr n2 = 255-j (l-part)
    int n1 = 511 - j, n2 = 255 - j;
    float wn1 = wing[n1], wn2 = wing[n2];
    float vA_l = Cj256.x * wn2;                 // even row tA contribution (l)
    float vAB  = Cj.x * wn1 + Cj256.y * wn2;    // odd row tB: A.r + B.l (owned)
    float vB_r = Cj.y * wn1;                    // even row tB+1 contribution (r)
    out[(b * T_LEN + tB) * 256 + n2] = vAB;
    int su = (b * 500 + u) * 256 + n2;
    sbl[su] = vA_l;
    sbr[su] = vB_r;
  }
}

// ---- even rows: out[b, 2u, n] = l(2u) + r(2u-1 mod 1000) ---------------------
__global__ __launch_bounds__(256) void k_even(const float* __restrict__ sbl,
    const float* __restrict__ sbr, float* __restrict__ out) {
  int idx = blockIdx.x * 256 + threadIdx.x;   // 1,024,000
  int n = idx & 255;
  int bu = idx >> 8;                          // b*500 + u
  int u = bu % 500, b = bu / 500;
  int up = (u == 0) ? 499 : u - 1;
  out[(b * T_LEN + 2 * u) * 256 + n] = sbl[idx] + sbr[(b * 500 + up) * 256 + n];
}

extern "C" void kernel_launch(void* const* d_in, const int* in_sizes, int n_in,
                              void* d_out, int out_size, void* d_ws, size_t ws_size,
                              hipStream_t stream) {
  const float* x  = (const float*)d_in[0];
  const float* z  = (const float*)d_in[1];
  const float* W1 = (const float*)d_in[2];
  const float* b1 = (const float*)d_in[3];
  const float* W2 = (const float*)d_in[4];
  const float* b2 = (const float*)d_in[5];
  const float* W3 = (const float*)d_in[6];
  const float* b3 = (const float*)d_in[7];
  const float* W4 = (const float*)d_in[8];
  const float* b4 = (const float*)d_in[9];

  float* ws   = (float*)d_ws;
  __hip_bfloat16* h3bf = (__hip_bfloat16*)ws;              // 1,024,000 f32 slots
  float* Pb   = ws + 1024000;            // 1,792,000 (single K-summed P)
  float* sbl  = ws + 8192000;            // 1,024,000
  float* sbr  = ws + 9216000;            // 1,024,000
  _Float16* W1p = (_Float16*)(ws + 10240000);              // 73,728 halves
  _Float16* W2p = (_Float16*)(ws + 10301440);              // 24,576 halves
  _Float16* W3p = (_Float16*)(ws + 10326016);              // 24,576 halves
  __hip_bfloat16* Wc = (__hip_bfloat16*)(ws + 10350592);   // 98,304 f32 slots
  float2* twTab = (float2*)(ws + 10448896);                // 1020 float2
  float* winTab = ws + 10450944;                           // 512
  float* out = (float*)d_out;

  dim3 blk(256);
  k_prep<<<480, blk, 0, stream>>>(W1, W2, W3, W1p, W2p, W3p);

  dim3 gc(32, B_N, 3);             // z 0,1: conv planes; z 2: table prep
  k_convfused<<<gc, blk, 0, stream>>>(x, W1p, b1, W2p, b2, W3p, b3, h3bf,
                                      W4, Wc, twTab, winTab);
  dim3 g4(32, B_N);                // single-pass K=768
  k_conv4m<<<g4, blk, 0, stream>>>(h3bf, Wc, b4, Pb);
  dim3 gf(T_LEN / 2, B_N);         // (500, 8)
  k_fft<<<gf, blk, 0, stream>>>(Pb, z, twTab, winTab, out, sbl, sbr);
  k_even<<<4000, blk, 0, stream>>>(sbl, sbr, out);
}

// Round 9
// 150.400 us; speedup vs baseline: 1.0237x; 1.0237x over previous
//
#include <hip/hip_runtime.h>
#include <hip/hip_bf16.h>

#define T_LEN 1000
#define B_N 8
#define IN_CH 80
#define CONV_CH 256
#define CCEP_N 222

typedef short s8v __attribute__((ext_vector_type(8)));      // 8 bf16 (4 VGPRs)
typedef _Float16 h8v __attribute__((ext_vector_type(8)));   // 8 fp16 (4 VGPRs)
typedef float f16v __attribute__((ext_vector_type(16)));    // MFMA 32x32 acc

#define TWO_PI 6.28318530717958647692f

// ===================== prep kernel: conv1-3 weights only ======================
// [0,288): W1p [9][256][32] fp16, k = chg*32+kloc in [0,288), kappa=k/96, i=k%96
//          (i>=80 zero-padded);
// [288,384): W2p [3][256][32], k in [0,96), kappa=k>>5, iloc=k&31;
// [384,480): W3p same.
__global__ __launch_bounds__(256) void k_prep(
    const float* __restrict__ W1, const float* __restrict__ W2,
    const float* __restrict__ W3,
    _Float16* __restrict__ W1p, _Float16* __restrict__ W2p,
    _Float16* __restrict__ W3p) {
  const int bid = blockIdx.x, tid = threadIdx.x;
  if (bid < 288) {
    int e = bid * 256 + tid;                 // 73728 = 9*8192
    int kloc = e & 31, n = (e >> 5) & 255, chg = e >> 13;
    int k = chg * 32 + kloc;
    int kappa = k / 96, i = k - kappa * 96;
    W1p[e] = (i < IN_CH) ? (_Float16)W1[n * 240 + i * 3 + kappa] : (_Float16)0.f;
  } else if (bid < 384) {
    int e = (bid - 288) * 256 + tid;         // 24576 = 3*8192
    int kloc = e & 31, n = (e >> 5) & 255, chg = e >> 13;
    int k = chg * 32 + kloc;
    int kappa = k >> 5, iloc = k & 31;
    W2p[e] = (_Float16)W2[n * 96 + iloc * 3 + kappa];
  } else {
    int e = (bid - 384) * 256 + tid;
    int kloc = e & 31, n = (e >> 5) & 255, chg = e >> 13;
    int k = chg * 32 + kloc;
    int kappa = k >> 5, iloc = k & 31;
    W3p[e] = (_Float16)W3[n * 96 + iloc * 3 + kappa];
  }
}

// ===== conv1-3 FULLY FUSED as MFMA fp16 GEMMs, h1/h2 in LDS ===================
// grid (32, 8, 3). z in {0,1}: conv planes (block = 32 t x 128 ch). z == 2:
// table-prep plane (256 blocks): Wc (conv4 bf16 weights, /quef fused) +
// twiddle + window tables. No shared state between planes; consumers
// (k_conv4m, k_fft) launch later on the same stream.
// Conv: halo via overlapping M-tiles: L1 computes h1 rows t0-2..t0+33 (tiles
// at offset 0 and +4, tile-b stores only row>=28); L2 computes h2 rows
// t0-1..t0+32 (offsets 0 and +2, tile-b stores row>=30); L3 one tile.
// Rows outside [0,T) zeroed at store (reference zero-pads each layer).
// x staged fp32->fp16 in-kernel. B double-buffered per 32-k chunk (pitch 48).
#define XP2 112   // xs pitch (halves): 224B, 4-way max bank aliasing
#define HP2 144   // h1s/h2s pitch: 288B, 4-way
#define BP2 48    // Bs pitch: 96B, 4-way

__global__ __launch_bounds__(256) void k_convfused(
    const float* __restrict__ x,
    const _Float16* __restrict__ W1p, const float* __restrict__ b1,
    const _Float16* __restrict__ W2p, const float* __restrict__ b2,
    const _Float16* __restrict__ W3p, const float* __restrict__ b3,
    __hip_bfloat16* __restrict__ out,
    const float* __restrict__ W4, __hip_bfloat16* __restrict__ Wc,
    float2* __restrict__ twTab, float* __restrict__ winTab) {
  const int tid = threadIdx.x;

  if (blockIdx.z == 2) {
    // ---- table-prep plane: Wc (196608) + twiddle (1020) + window (512) ----
    int blk = blockIdx.y * 32 + blockIdx.x;        // 0..255
    for (int e = blk * 256 + tid; e < 196608 + 1532; e += 65536) {
      if (e < 196608) {
        int kloc = e & 31, n = (e >> 5) & 255, chg = e >> 13;
        int kp = chg * 32 + kloc;
        int kappa = kp >> 8, i = kp & 255;
        float v = 0.f;
        if (n < CCEP_N) {
          float invq = 1.f / (float)((n < 111) ? (111 - n) : (n - 110));
          v = W4[n * 768 + i * 3 + kappa] * invq;
        }
        Wc[e] = __float2bfloat16(v);
      } else {
        int e2 = e - 196608;
        if (e2 < 1020) {
          int Q, off;
          if (e2 < 768)       { Q = 256; off = 0; }
          else if (e2 < 960)  { Q = 64;  off = 768; }
          else if (e2 < 1008) { Q = 16;  off = 960; }
          else                { Q = 4;   off = 1008; }
          int rem = e2 - off;
          int r = rem / Q, pos = rem - r * Q;
          float ang = (TWO_PI * (float)((r + 1) * pos)) / (float)(4 * Q);
          float s, c;
          sincosf(ang, &s, &c);
          twTab[e2] = make_float2(c, s);
        } else if (e2 < 1532) {
          int n = e2 - 1020;
          winTab[n] = (0.5f - 0.5f * cosf(TWO_PI * (float)n / 512.f)) * (1.f / 1024.f);
        }
      }
    }
    return;
  }

  const int mb = blockIdx.x, b = blockIdx.y, z = blockIdx.z;
  const int t0 = mb * 32;
  const int w = tid >> 6, lane = tid & 63;
  const int lm = lane & 31, half = lane >> 5;
  const int n0loc = w * 32;                  // wave's N-tile within block's 128
  const int c = z * 128 + n0loc + lm;        // global out channel

  __shared__ _Float16 xs[38 * XP2];          // rows t0-3 .. t0+34
  __shared__ _Float16 h1s[36 * HP2];         // idx = t-(t0-2), 0..35
  __shared__ _Float16 h2s[34 * HP2];         // idx = t-(t0-1), 0..33
  __shared__ _Float16 Bs[2][128 * BP2];

  // ---- stage x (fp32 -> fp16), zero-pad t outside [0,T) and ch >= 80 ----
  for (int e = tid; e < 38 * 96; e += 256) {
    int rr = e / 96, cc = e - rr * 96;
    int t = t0 - 3 + rr;
    float v = (cc < IN_CH && t >= 0 && t < T_LEN)
                  ? x[(b * T_LEN + t) * IN_CH + cc] : 0.f;
    xs[rr * XP2 + cc] = (_Float16)v;
  }
  {
    const _Float16* src = W1p + z * 4096;    // chg 0, this block's 128 n
    for (int e = tid; e < 512; e += 256) {
      int nl = e >> 2, c4 = e & 3;
      *(uint4*)(Bs[0] + nl * BP2 + c4 * 8) = *(const uint4*)(src + nl * 32 + c4 * 8);
    }
  }
  __syncthreads();

  // ---------- layer 1: K=288 (9 chgs), M-tiles at +0 and +4 ----------
  {
    f16v a0 = {}, a1 = {};
    for (int chg = 0; chg < 9; ++chg) {
      const int p = chg & 1;
      if (chg + 1 < 9) {
        const _Float16* src = W1p + (size_t)(chg + 1) * 8192 + z * 4096;
        for (int e = tid; e < 512; e += 256) {
          int nl = e >> 2, c4 = e & 3;
          *(uint4*)(Bs[p ^ 1] + nl * BP2 + c4 * 8) = *(const uint4*)(src + nl * 32 + c4 * 8);
        }
      }
#pragma unroll
      for (int s = 0; s < 2; ++s) {
        const int c16 = chg * 2 + s;
        const int kappa = c16 / 6;
        const int icol = (c16 - kappa * 6) * 16;
        h8v bf = *(const h8v*)(Bs[p] + (n0loc + lm) * BP2 + s * 16 + half * 8);
        h8v aa0 = *(const h8v*)(xs + (lm + kappa) * XP2 + icol + half * 8);
        h8v aa1 = *(const h8v*)(xs + (lm + kappa + 4) * XP2 + icol + half * 8);
        a0 = __builtin_amdgcn_mfma_f32_32x32x16_f16(aa0, bf, a0, 0, 0, 0);
        a1 = __builtin_amdgcn_mfma_f32_32x32x16_f16(aa1, bf, a1, 0, 0, 0);
      }
      __syncthreads();
    }
    const float bv = b1[c];
#pragma unroll
    for (int reg = 0; reg < 16; ++reg) {
      int row = (reg & 3) + 8 * (reg >> 2) + 4 * half;
      {
        int t = t0 - 2 + row;                // tile a -> idx row
        float v = (t >= 0 && t < T_LEN) ? fmaxf(a0[reg] + bv, 0.f) : 0.f;
        h1s[row * HP2 + n0loc + lm] = (_Float16)v;
      }
      if (row >= 28) {                       // tile b -> idx row+4 (32..35)
        int t = t0 + 2 + row;
        float v = (t >= 0 && t < T_LEN) ? fmaxf(a1[reg] + bv, 0.f) : 0.f;
        h1s[(row + 4) * HP2 + n0loc + lm] = (_Float16)v;
      }
    }
  }
  {
    const _Float16* src = W2p + z * 4096;    // Bs[0] free after loop barrier
    for (int e = tid; e < 512; e += 256) {
      int nl = e >> 2, c4 = e & 3;
      *(uint4*)(Bs[0] + nl * BP2 + c4 * 8) = *(const uint4*)(src + nl * 32 + c4 * 8);
    }
  }
  __syncthreads();

  // ---------- layer 2: K=96 grouped (3 chgs), M-tiles at +0 and +2 ----------
  {
    f16v a0 = {}, a1 = {};
    for (int chg = 0; chg < 3; ++chg) {
      const int p = chg & 1;
      if (chg + 1 < 3) {
        const _Float16* src = W2p + (size_t)(chg + 1) * 8192 + z * 4096;
        for (int e = tid; e < 512; e += 256) {
          int nl = e >> 2, c4 = e & 3;
          *(uint4*)(Bs[p ^ 1] + nl * BP2 + c4 * 8) = *(const uint4*)(src + nl * 32 + c4 * 8);
        }
      }
#pragma unroll
      for (int s = 0; s < 2; ++s) {
        const int c16 = chg * 2 + s;
        const int kappa = c16 >> 1;
        const int icol = n0loc + (c16 & 1) * 16;   // in-group == N-tile
        h8v bf = *(const h8v*)(Bs[p] + (n0loc + lm) * BP2 + s * 16 + half * 8);
        h8v aa0 = *(const h8v*)(h1s + (lm + kappa) * HP2 + icol + half * 8);
        h8v aa1 = *(const h8v*)(h1s + (lm + kappa + 2) * HP2 + icol + half * 8);
        a0 = __builtin_amdgcn_mfma_f32_32x32x16_f16(aa0, bf, a0, 0, 0, 0);
        a1 = __builtin_amdgcn_mfma_f32_32x32x16_f16(aa1, bf, a1, 0, 0, 0);
      }
      __syncthreads();
    }
    const float bv = b2[c];
#pragma unroll
    for (int reg = 0; reg < 16; ++reg) {
      int row = (reg & 3) + 8 * (reg >> 2) + 4 * half;
      {
        int t = t0 - 1 + row;                // tile a -> idx row
        float v = (t >= 0 && t < T_LEN) ? fmaxf(a0[reg] + bv, 0.f) : 0.f;
        h2s[row * HP2 + n0loc + lm] = (_Float16)v;
      }
      if (row >= 30) {                       // tile b -> idx row+2 (32..33)
        int t = t0 + 1 + row;
        float v = (t >= 0 && t < T_LEN) ? fmaxf(a1[reg] + bv, 0.f) : 0.f;
        h2s[(row + 2) * HP2 + n0loc + lm] = (_Float16)v;
      }
    }
  }
  {
    const _Float16* src = W3p + z * 4096;
    for (int e = tid; e < 512; e += 256) {
      int nl = e >> 2, c4 = e & 3;
      *(uint4*)(Bs[0] + nl * BP2 + c4 * 8) = *(const uint4*)(src + nl * 32 + c4 * 8);
    }
  }
  __syncthreads();

  // ---------- layer 3: K=96 grouped (3 chgs), one M-tile ----------
  {
    f16v a0 = {};
    for (int chg = 0; chg < 3; ++chg) {
      const int p = chg & 1;
      if (chg + 1 < 3) {
        const _Float16* src = W3p + (size_t)(chg + 1) * 8192 + z * 4096;
        for (int e = tid; e < 512; e += 256) {
          int nl = e >> 2, c4 = e & 3;
          *(uint4*)(Bs[p ^ 1] + nl * BP2 + c4 * 8) = *(const uint4*)(src + nl * 32 + c4 * 8);
        }
      }
#pragma unroll
      for (int s = 0; s < 2; ++s) {
        const int c16 = chg * 2 + s;
        const int kappa = c16 >> 1;
        const int icol = n0loc + (c16 & 1) * 16;
        h8v bf = *(const h8v*)(Bs[p] + (n0loc + lm) * BP2 + s * 16 + half * 8);
        h8v aa = *(const h8v*)(h2s + (lm + kappa) * HP2 + icol + half * 8);
        a0 = __builtin_amdgcn_mfma_f32_32x32x16_f16(aa, bf, a0, 0, 0, 0);
      }
      __syncthreads();
    }
    const float bv = b3[c];
#pragma unroll
    for (int reg = 0; reg < 16; ++reg) {
      int row = (reg & 3) + 8 * (reg >> 2) + 4 * half;
      int t = t0 + row;
      if (t < T_LEN)
        out[(size_t)(b * T_LEN + t) * CONV_CH + c] =
            __float2bfloat16(fmaxf(a0[reg] + bv, 0.f));
    }
  }
}

// ============ conv4 as MFMA GEMM, K-split x4: 512 blocks (2/CU) ===============
// Round-7 proven structure: parallelism (2 blocks/CU) beats the extra P-partial
// HBM traffic (round-8 single-pass at 1 block/CU exposed the per-chunk barrier
// drain and regressed).
#define APITCH 264
#define BPITCH 40
#define PSTRIDE 1792000
__global__ __launch_bounds__(256) void k_conv4m(
    const __hip_bfloat16* __restrict__ h3, const __hip_bfloat16* __restrict__ Wc,
    const float* __restrict__ bias, float* __restrict__ Pbase) {
  const int mb = blockIdx.x, b = blockIdx.y, ks = blockIdx.z;
  float* __restrict__ P = Pbase + (size_t)ks * PSTRIDE;
  const int t0 = mb * 64;
  const int tid = threadIdx.x;
  const int w = tid >> 6, lane = tid & 63;
  const int wm = w >> 1, wn = w & 1;
  const int lm = lane & 31, half = lane >> 5;

  __shared__ short h3s[67 * APITCH];
  __shared__ short Bs[2][256 * BPITCH];

  const ushort* h3u = (const ushort*)h3;
  for (int g = tid; g < 67 * 64; g += 256) {
    int rr = g >> 6, c4 = g & 63;
    int t = t0 + rr - 1;
    uint2 v = make_uint2(0u, 0u);
    if (t >= 0 && t < T_LEN)
      v = *(const uint2*)(h3u + (b * T_LEN + t) * CONV_CH + c4 * 4);
    *(uint2*)(h3s + rr * APITCH + c4 * 4) = v;
  }

  const ushort* Wu = (const ushort*)(Wc) + (size_t)(ks * 6) * 8192;
#pragma unroll
  for (int it = 0; it < 4; ++it) {
    int idx = (it * 256 + tid) * 8;
    uint4 v = *(const uint4*)(Wu + idx);
    int n = idx >> 5, kloc = idx & 31;
    *(uint4*)(Bs[0] + n * BPITCH + kloc) = v;
  }
  __syncthreads();

  f16v acc0 = {}, acc1 = {}, acc2 = {}, acc3 = {};

  for (int ch = 0; ch < 6; ++ch) {
    const int p = ch & 1;
    if (ch < 5) {
      const ushort* src = Wu + (ch + 1) * 8192;
#pragma unroll
      for (int it = 0; it < 4; ++it) {
        int idx = (it * 256 + tid) * 8;
        uint4 v = *(const uint4*)(src + idx);
        int n = idx >> 5, kloc = idx & 31;
        *(uint4*)(Bs[p ^ 1] + n * BPITCH + kloc) = v;
      }
    }
#pragma unroll
    for (int s = 0; s < 2; ++s) {
      int k0 = ks * 192 + ch * 32 + s * 16;
      int kappa = k0 >> 8, i0 = k0 & 255;
      s8v a = *(const s8v*)(h3s + (wm * 32 + lm + kappa) * APITCH + i0 + half * 8);
      const short* bp = Bs[p] + (wn * 128 + lm) * BPITCH + s * 16 + half * 8;
      s8v b0 = *(const s8v*)(bp);
      s8v b1 = *(const s8v*)(bp + 32 * BPITCH);
      s8v b2 = *(const s8v*)(bp + 64 * BPITCH);
      s8v b3 = *(const s8v*)(bp + 96 * BPITCH);
      acc0 = __builtin_amdgcn_mfma_f32_32x32x16_bf16(a, b0, acc0, 0, 0, 0);
      acc1 = __builtin_amdgcn_mfma_f32_32x32x16_bf16(a, b1, acc1, 0, 0, 0);
      acc2 = __builtin_amdgcn_mfma_f32_32x32x16_bf16(a, b2, acc2, 0, 0, 0);
      acc3 = __builtin_amdgcn_mfma_f32_32x32x16_bf16(a, b3, acc3, 0, 0, 0);
    }
    __syncthreads();
  }

  const int col = lm;
#pragma unroll
  for (int nt = 0; nt < 4; ++nt) {
    int c = wn * 128 + nt * 32 + col;
    if (c >= CCEP_N) continue;
    float bq = 0.f;
    if (ks == 0) {
      float invq = 1.f / (float)((c < 111) ? (111 - c) : (c - 110));
      bq = bias[c] * invq;
    }
    const f16v* A = (nt == 0) ? &acc0 : (nt == 1) ? &acc1 : (nt == 2) ? &acc2 : &acc3;
#pragma unroll
    for (int reg = 0; reg < 16; ++reg) {
      int row = (reg & 3) + 8 * (reg >> 2) + 4 * half;
      int t = t0 + wm * 32 + row;
      if (t < T_LEN)
        P[(size_t)(b * T_LEN + t) * 224 + c] = (*A)[reg] + bq;
    }
  }
}

// ============================ fused FFT kernel (2 frames/block) ===============
// Frames tA=2u, tB=2u+1. Two packed forward FFTs (c + i*fr per frame); S_A, S_B
// Hermitian -> ONE inverse: Z = S_A + i*S_B, IFFT(Z) = C_A + i*C_B (both real).
// Odd rows stored directly; even-row contributions spilled to sbl/sbr; no atomics.
__device__ __forceinline__ float2 cmul(float2 a, float2 b) {
  return make_float2(fmaf(a.x, b.x, -(a.y * b.y)), fmaf(a.x, b.y, a.y * b.x));
}
__device__ __forceinline__ float2 cadd(float2 a, float2 b) { return make_float2(a.x + b.x, a.y + b.y); }
__device__ __forceinline__ float2 csub(float2 a, float2 b) { return make_float2(a.x - b.x, a.y - b.y); }

#define LIDX(i) ((i) + ((i) >> 2))

template <int Q, int OFF>
__device__ __forceinline__ void fwd_stage2(float2* __restrict__ A,
    float2* __restrict__ B, const float2* __restrict__ Tw, int j) {
  const int pos = j & (Q - 1);
  const int base = ((j - pos) << 2) + pos;
  float2 e1 = Tw[OFF + pos], e2 = Tw[OFF + Q + pos], e3 = Tw[OFF + 2 * Q + pos];
  const float2 w1 = make_float2(e1.x, -e1.y);
  const float2 w2 = make_float2(e2.x, -e2.y);
  const float2 w3 = make_float2(e3.x, -e3.y);
#pragma unroll
  for (int arr = 0; arr < 2; ++arr) {
    float2* X = arr ? B : A;
    float2 a = X[LIDX(base)], b = X[LIDX(base + Q)];
    float2 cc = X[LIDX(base + 2 * Q)], d = X[LIDX(base + 3 * Q)];
    float2 t0 = cadd(a, cc), t1 = csub(a, cc), t2 = cadd(b, d), bd = csub(b, d);
    float2 t3 = make_float2(bd.y, -bd.x);
    X[LIDX(base)]         = cadd(t0, t2);
    X[LIDX(base + Q)]     = cmul(cadd(t1, t3), w1);
    X[LIDX(base + 2 * Q)] = cmul(csub(t0, t2), w2);
    X[LIDX(base + 3 * Q)] = cmul(csub(t1, t3), w3);
  }
}

template <int Q, int OFF>
__device__ __forceinline__ void inv_stage_t(float2* __restrict__ X,
    const float2* __restrict__ Tw, int j) {
  const int pos = j & (Q - 1);
  const int base = ((j - pos) << 2) + pos;
  const float2 w1 = Tw[OFF + pos];
  const float2 w2 = Tw[OFF + Q + pos];
  const float2 w3 = Tw[OFF + 2 * Q + pos];
  float2 a = X[LIDX(base)];
  float2 b = cmul(X[LIDX(base + Q)], w1);
  float2 cc = cmul(X[LIDX(base + 2 * Q)], w2);
  float2 d = cmul(X[LIDX(base + 3 * Q)], w3);
  float2 t0 = cadd(a, cc), t1 = csub(a, cc), t2 = cadd(b, d), bd = csub(b, d);
  float2 t3 = make_float2(-bd.y, bd.x);
  X[LIDX(base)]         = cadd(t0, t2);
  X[LIDX(base + Q)]     = cadd(t1, t3);
  X[LIDX(base + 2 * Q)] = csub(t0, t2);
  X[LIDX(base + 3 * Q)] = csub(t1, t3);
}

__device__ __forceinline__ int rev4d(int v) {
  return ((v & 3) << 6) | (((v >> 2) & 3) << 4) | (((v >> 4) & 3) << 2) | ((v >> 6) & 3);
}

// grid (500, 8)
__global__ __launch_bounds__(256) void k_fft(const float* __restrict__ Pb,
    const float* __restrict__ z, const float2* __restrict__ twg,
    const float* __restrict__ wing, float* __restrict__ out,
    float* __restrict__ sbl, float* __restrict__ sbr) {
  const int u = blockIdx.x, b = blockIdx.y;
  const int tA = 2 * u, tB = tA + 1;
  const int btA = b * T_LEN + tA, btB = btA + 1;
  const int j = threadIdx.x;
  __shared__ float2 WlA[1280];
  __shared__ float2 WlB[1280];
  __shared__ float2 Tws[1020];
  for (int e = j; e < 1020; e += 256) Tws[e] = twg[e];

  const float* zb = z + b * 256000;
  float f0A = 0.f, fS, f1B = 0.f;
  {
    int zi0 = tA * 256 + j - 255;
    f0A = (zi0 >= 0) ? zb[zi0] : 0.f;
    fS = zb[tA * 256 + j + 1];
    int zi2 = tB * 256 + j + 1;
    f1B = (zi2 < 256000) ? zb[zi2] : 0.f;
  }
  float c1A = 0.f, c2A = 0.f, c1B = 0.f, c2B = 0.f;
  if (j >= 145) {
    int mA = btA * 224 + (j - 145), mB = btB * 224 + (j - 145);
    c1A = (Pb[mA] + Pb[mA + PSTRIDE]) + (Pb[mA + 2 * PSTRIDE] + Pb[mA + 3 * PSTRIDE]);
    c1B = (Pb[mB] + Pb[mB + PSTRIDE]) + (Pb[mB + 2 * PSTRIDE] + Pb[mB + 3 * PSTRIDE]);
  }
  if (j < 111) {
    int mA = btA * 224 + (j + 111), mB = btB * 224 + (j + 111);
    c2A = (Pb[mA] + Pb[mA + PSTRIDE]) + (Pb[mA + 2 * PSTRIDE] + Pb[mA + 3 * PSTRIDE]);
    c2B = (Pb[mB] + Pb[mB + PSTRIDE]) + (Pb[mB + 2 * PSTRIDE] + Pb[mB + 3 * PSTRIDE]);
  }
  __syncthreads();

  {
    float2 e1 = Tws[j], e2 = Tws[256 + j], e3 = Tws[512 + j];
    const float2 w1 = make_float2(e1.x, -e1.y);
    const float2 w2 = make_float2(e2.x, -e2.y);
    const float2 w3 = make_float2(e3.x, -e3.y);
    {
      float2 t0 = make_float2(c2A, f0A);
      float2 t1 = make_float2(-c2A, f0A);
      float2 t2 = make_float2(c1A, fS);
      float2 t3 = make_float2(fS, -c1A);
      WlA[LIDX(j)]       = cadd(t0, t2);
      WlA[LIDX(j + 256)] = cmul(cadd(t1, t3), w1);
      WlA[LIDX(j + 512)] = cmul(csub(t0, t2), w2);
      WlA[LIDX(j + 768)] = cmul(csub(t1, t3), w3);
    }
    {
      float2 t0 = make_float2(c2B, fS);
      float2 t1 = make_float2(-c2B, fS);
      float2 t2 = make_float2(c1B, f1B);
      float2 t3 = make_float2(f1B, -c1B);
      WlB[LIDX(j)]       = cadd(t0, t2);
      WlB[LIDX(j + 256)] = cmul(cadd(t1, t3), w1);
      WlB[LIDX(j + 512)] = cmul(csub(t0, t2), w2);
      WlB[LIDX(j + 768)] = cmul(csub(t1, t3), w3);
    }
  }
  __syncthreads();

  fwd_stage2<64, 768>(WlA, WlB, Tws, j);  __syncthreads();
  fwd_stage2<16, 960>(WlA, WlB, Tws, j);  __syncthreads();
  fwd_stage2<4, 1008>(WlA, WlB, Tws, j);  __syncthreads();

  const int base = 4 * j;
  float2 XA[4], XB[4];
  {
    float2 u0 = WlA[LIDX(base)], u1 = WlA[LIDX(base + 1)];
    float2 u2 = WlA[LIDX(base + 2)], u3 = WlA[LIDX(base + 3)];
    float2 t0 = cadd(u0, u2), t1 = csub(u0, u2), t2 = cadd(u1, u3), bd = csub(u1, u3);
    float2 t3 = make_float2(bd.y, -bd.x);
    XA[0] = cadd(t0, t2); XA[1] = cadd(t1, t3); XA[2] = csub(t0, t2); XA[3] = csub(t1, t3);
  }
  {
    float2 u0 = WlB[LIDX(base)], u1 = WlB[LIDX(base + 1)];
    float2 u2 = WlB[LIDX(base + 2)], u3 = WlB[LIDX(base + 3)];
    float2 t0 = cadd(u0, u2), t1 = csub(u0, u2), t2 = cadd(u1, u3), bd = csub(u1, u3);
    float2 t3 = make_float2(bd.y, -bd.x);
    XB[0] = cadd(t0, t2); XB[1] = cadd(t1, t3); XB[2] = csub(t0, t2); XB[3] = csub(t1, t3);
  }
#pragma unroll
  for (int q = 0; q < 4; ++q) { WlA[LIDX(base + q)] = XA[q]; WlB[LIDX(base + q)] = XB[q]; }
  __syncthreads();

  const int r0 = rev4d(j);
  const bool self0 = (r0 == 0);
  const int jp = self0 ? 0 : rev4d((256 - r0) & 255);
  float2 PA[4], PB[4];
#pragma unroll
  for (int q = 0; q < 4; ++q) { PA[q] = WlA[LIDX(4 * jp + q)]; PB[q] = WlB[LIDX(4 * jp + q)]; }
  float2 Z[4];
#pragma unroll
  for (int q = 0; q < 4; ++q) {
    float2 SA, SB;
    {
      float2 A = XA[q];
      float2 Bc = self0 ? PA[(4 - q) & 3] : PA[3 - q];
      float2 Y = make_float2(0.5f * (A.x + Bc.x), 0.5f * (A.y - Bc.y));
      float2 F = make_float2(0.5f * (A.y + Bc.y), -0.5f * (A.x - Bc.x));
      float mag = __expf(Y.x * 2.30258509299404568402f);
      float sy, cy;
      __sincosf(Y.y, &sy, &cy);
      float gr = mag * cy, gi = mag * sy;
      SA = make_float2(fmaf(F.x, gr, F.y * gi), fmaf(F.x, gi, -(F.y * gr)));
    }
    {
      float2 A = XB[q];
      float2 Bc = self0 ? PB[(4 - q) & 3] : PB[3 - q];
      float2 Y = make_float2(0.5f * (A.x + Bc.x), 0.5f * (A.y - Bc.y));
      float2 F = make_float2(0.5f * (A.y + Bc.y), -0.5f * (A.x - Bc.x));
      float mag = __expf(Y.x * 2.30258509299404568402f);
      float sy, cy;
      __sincosf(Y.y, &sy, &cy);
      float gr = mag * cy, gi = mag * sy;
      SB = make_float2(fmaf(F.x, gr, F.y * gi), fmaf(F.x, gi, -(F.y * gr)));
    }
    Z[q] = make_float2(SA.x - SB.y, SA.y + SB.x);   // S_A + i*S_B
  }
  __syncthreads();

  {
    float2 t0 = cadd(Z[0], Z[2]), t1 = csub(Z[0], Z[2]), t2 = cadd(Z[1], Z[3]), bd = csub(Z[1], Z[3]);
    float2 t3 = make_float2(-bd.y, bd.x);
    WlA[LIDX(base)]     = cadd(t0, t2);
    WlA[LIDX(base + 1)] = cadd(t1, t3);
    WlA[LIDX(base + 2)] = csub(t0, t2);
    WlA[LIDX(base + 3)] = csub(t1, t3);
  }
  __syncthreads();

  inv_stage_t<4, 1008>(WlA, Tws, j);  __syncthreads();
  inv_stage_t<16, 960>(WlA, Tws, j);  __syncthreads();
  inv_stage_t<64, 768>(WlA, Tws, j);  __syncthreads();

  {
    float2 w1 = Tws[j], w2 = Tws[256 + j], w3 = Tws[512 + j];
    float2 a = WlA[LIDX(j)];
    float2 bb = cmul(WlA[LIDX(j + 256)], w1);
    float2 cc = cmul(WlA[LIDX(j + 512)], w2);
    float2 d = cmul(WlA[LIDX(j + 768)], w3);
    float2 t0 = cadd(a, cc), t1 = csub(a, cc), t2 = cadd(bb, d), bd = csub(bb, d);
    float2 t3 = make_float2(-bd.y, bd.x);
    float2 Cj    = cadd(t0, t2);   // C[j]     -> corr n1 = 511-j (r-part)
    float2 Cj256 = cadd(t1, t3);   // C[j+256] -> corr n2 = 255-j (l-part)
    int n1 = 511 - j, n2 = 255 - j;
    float wn1 = wing[n1], wn2 = wing[n2];
    float vA_l = Cj256.x * wn2;                 // even row tA contribution (l)
    float vAB  = Cj.x * wn1 + Cj256.y * wn2;    // odd row tB: A.r + B.l (owned)
    float vB_r = Cj.y * wn1;                    // even row tB+1 contribution (r)
    out[(b * T_LEN + tB) * 256 + n2] = vAB;
    int su = (b * 500 + u) * 256 + n2;
    sbl[su] = vA_l;
    sbr[su] = vB_r;
  }
}

// ---- even rows: out[b, 2u, n] = l(2u) + r(2u-1 mod 1000) ---------------------
__global__ __launch_bounds__(256) void k_even(const float* __restrict__ sbl,
    const float* __restrict__ sbr, float* __restrict__ out) {
  int idx = blockIdx.x * 256 + threadIdx.x;   // 1,024,000
  int n = idx & 255;
  int bu = idx >> 8;                          // b*500 + u
  int u = bu % 500, b = bu / 500;
  int up = (u == 0) ? 499 : u - 1;
  out[(b * T_LEN + 2 * u) * 256 + n] = sbl[idx] + sbr[(b * 500 + up) * 256 + n];
}

extern "C" void kernel_launch(void* const* d_in, const int* in_sizes, int n_in,
                              void* d_out, int out_size, void* d_ws, size_t ws_size,
                              hipStream_t stream) {
  const float* x  = (const float*)d_in[0];
  const float* z  = (const float*)d_in[1];
  const float* W1 = (const float*)d_in[2];
  const float* b1 = (const float*)d_in[3];
  const float* W2 = (const float*)d_in[4];
  const float* b2 = (const float*)d_in[5];
  const float* W3 = (const float*)d_in[6];
  const float* b3 = (const float*)d_in[7];
  const float* W4 = (const float*)d_in[8];
  const float* b4 = (const float*)d_in[9];

  float* ws   = (float*)d_ws;
  __hip_bfloat16* h3bf = (__hip_bfloat16*)ws;              // 1,024,000 f32 slots
  float* Pb   = ws + 1024000;            // 4 x 1,792,000 = 7,168,000
  float* sbl  = ws + 8192000;            // 1,024,000
  float* sbr  = ws + 9216000;            // 1,024,000
  _Float16* W1p = (_Float16*)(ws + 10240000);              // 73,728 halves
  _Float16* W2p = (_Float16*)(ws + 10301440);              // 24,576 halves
  _Float16* W3p = (_Float16*)(ws + 10326016);              // 24,576 halves
  __hip_bfloat16* Wc = (__hip_bfloat16*)(ws + 10350592);   // 98,304 f32 slots
  float2* twTab = (float2*)(ws + 10448896);                // 1020 float2
  float* winTab = ws + 10450944;                           // 512
  float* out = (float*)d_out;

  dim3 blk(256);
  k_prep<<<480, blk, 0, stream>>>(W1, W2, W3, W1p, W2p, W3p);

  dim3 gc(32, B_N, 3);             // z 0,1: conv planes; z 2: table prep
  k_convfused<<<gc, blk, 0, stream>>>(x, W1p, b1, W2p, b2, W3p, b3, h3bf,
                                      W4, Wc, twTab, winTab);
  dim3 g4(16, B_N, 4);             // K-split x4 (round-7 proven)
  k_conv4m<<<g4, blk, 0, stream>>>(h3bf, Wc, b4, Pb);
  dim3 gf(T_LEN / 2, B_N);         // (500, 8)
  k_fft<<<gf, blk, 0, stream>>>(Pb, z, twTab, winTab, out, sbl, sbr);
  k_even<<<4000, blk, 0, stream>>>(sbl, sbr, out);
}

// Round 10
// 148.025 us; speedup vs baseline: 1.0401x; 1.0161x over previous
//
#include <hip/hip_runtime.h>
#include <hip/hip_bf16.h>

#define T_LEN 1000
#define B_N 8
#define IN_CH 80
#define CONV_CH 256
#define CCEP_N 222

typedef short s8v __attribute__((ext_vector_type(8)));      // 8 bf16 (4 VGPRs)
typedef _Float16 h8v __attribute__((ext_vector_type(8)));   // 8 fp16 (4 VGPRs)
typedef float f16v __attribute__((ext_vector_type(16)));    // MFMA 32x32 acc

#define TWO_PI 6.28318530717958647692f

// ===================== prep kernel: conv1-3 weights only ======================
// [0,288): W1p [9][256][32] fp16, k = chg*32+kloc in [0,288), kappa=k/96, i=k%96
//          (i>=80 zero-padded);
// [288,384): W2p [3][256][32], k in [0,96), kappa=k>>5, iloc=k&31;
// [384,480): W3p same.
__global__ __launch_bounds__(256) void k_prep(
    const float* __restrict__ W1, const float* __restrict__ W2,
    const float* __restrict__ W3,
    _Float16* __restrict__ W1p, _Float16* __restrict__ W2p,
    _Float16* __restrict__ W3p) {
  const int bid = blockIdx.x, tid = threadIdx.x;
  if (bid < 288) {
    int e = bid * 256 + tid;                 // 73728 = 9*8192
    int kloc = e & 31, n = (e >> 5) & 255, chg = e >> 13;
    int k = chg * 32 + kloc;
    int kappa = k / 96, i = k - kappa * 96;
    W1p[e] = (i < IN_CH) ? (_Float16)W1[n * 240 + i * 3 + kappa] : (_Float16)0.f;
  } else if (bid < 384) {
    int e = (bid - 288) * 256 + tid;         // 24576 = 3*8192
    int kloc = e & 31, n = (e >> 5) & 255, chg = e >> 13;
    int k = chg * 32 + kloc;
    int kappa = k >> 5, iloc = k & 31;
    W2p[e] = (_Float16)W2[n * 96 + iloc * 3 + kappa];
  } else {
    int e = (bid - 384) * 256 + tid;
    int kloc = e & 31, n = (e >> 5) & 255, chg = e >> 13;
    int k = chg * 32 + kloc;
    int kappa = k >> 5, iloc = k & 31;
    W3p[e] = (_Float16)W3[n * 96 + iloc * 3 + kappa];
  }
}

// ===== conv1-3 FULLY FUSED as MFMA fp16 GEMMs, h1/h2 in LDS ===================
// grid (32, 8, 3). z in {0,1}: conv planes (block = 32 t x 128 ch). z == 2:
// table-prep plane (256 blocks): Wc (conv4 bf16 weights, /quef fused) +
// twiddle + window tables. No shared state between planes; consumers
// (k_conv4m, k_fft) launch later on the same stream.
// Conv: halo via overlapping M-tiles: L1 computes h1 rows t0-2..t0+33 (tiles
// at offset 0 and +4, tile-b stores only row>=28); L2 computes h2 rows
// t0-1..t0+32 (offsets 0 and +2, tile-b stores row>=30); L3 one tile.
// Rows outside [0,T) zeroed at store (reference zero-pads each layer).
// x staged fp32->fp16 in-kernel. B double-buffered per 32-k chunk (pitch 48).
#define XP2 112   // xs pitch (halves): 224B, 4-way max bank aliasing
#define HP2 144   // h1s/h2s pitch: 288B, 4-way
#define BP2 48    // Bs pitch: 96B, 4-way

__global__ __launch_bounds__(256) void k_convfused(
    const float* __restrict__ x,
    const _Float16* __restrict__ W1p, const float* __restrict__ b1,
    const _Float16* __restrict__ W2p, const float* __restrict__ b2,
    const _Float16* __restrict__ W3p, const float* __restrict__ b3,
    __hip_bfloat16* __restrict__ out,
    const float* __restrict__ W4, __hip_bfloat16* __restrict__ Wc,
    float2* __restrict__ twTab, float* __restrict__ winTab) {
  const int tid = threadIdx.x;

  if (blockIdx.z == 2) {
    // ---- table-prep plane: Wc (196608) + twiddle (1020) + window (512) ----
    int blk = blockIdx.y * 32 + blockIdx.x;        // 0..255
    for (int e = blk * 256 + tid; e < 196608 + 1532; e += 65536) {
      if (e < 196608) {
        int kloc = e & 31, n = (e >> 5) & 255, chg = e >> 13;
        int kp = chg * 32 + kloc;
        int kappa = kp >> 8, i = kp & 255;
        float v = 0.f;
        if (n < CCEP_N) {
          float invq = 1.f / (float)((n < 111) ? (111 - n) : (n - 110));
          v = W4[n * 768 + i * 3 + kappa] * invq;
        }
        Wc[e] = __float2bfloat16(v);
      } else {
        int e2 = e - 196608;
        if (e2 < 1020) {
          int Q, off;
          if (e2 < 768)       { Q = 256; off = 0; }
          else if (e2 < 960)  { Q = 64;  off = 768; }
          else if (e2 < 1008) { Q = 16;  off = 960; }
          else                { Q = 4;   off = 1008; }
          int rem = e2 - off;
          int r = rem / Q, pos = rem - r * Q;
          float ang = (TWO_PI * (float)((r + 1) * pos)) / (float)(4 * Q);
          float s, c;
          sincosf(ang, &s, &c);
          twTab[e2] = make_float2(c, s);
        } else if (e2 < 1532) {
          int n = e2 - 1020;
          winTab[n] = (0.5f - 0.5f * cosf(TWO_PI * (float)n / 512.f)) * (1.f / 1024.f);
        }
      }
    }
    return;
  }

  const int mb = blockIdx.x, b = blockIdx.y, z = blockIdx.z;
  const int t0 = mb * 32;
  const int w = tid >> 6, lane = tid & 63;
  const int lm = lane & 31, half = lane >> 5;
  const int n0loc = w * 32;                  // wave's N-tile within block's 128
  const int c = z * 128 + n0loc + lm;        // global out channel

  __shared__ _Float16 xs[38 * XP2];          // rows t0-3 .. t0+34
  __shared__ _Float16 h1s[36 * HP2];         // idx = t-(t0-2), 0..35
  __shared__ _Float16 h2s[34 * HP2];         // idx = t-(t0-1), 0..33
  __shared__ _Float16 Bs[2][128 * BP2];

  // ---- stage x (fp32 -> fp16), zero-pad t outside [0,T) and ch >= 80 ----
  for (int e = tid; e < 38 * 96; e += 256) {
    int rr = e / 96, cc = e - rr * 96;
    int t = t0 - 3 + rr;
    float v = (cc < IN_CH && t >= 0 && t < T_LEN)
                  ? x[(b * T_LEN + t) * IN_CH + cc] : 0.f;
    xs[rr * XP2 + cc] = (_Float16)v;
  }
  {
    const _Float16* src = W1p + z * 4096;    // chg 0, this block's 128 n
    for (int e = tid; e < 512; e += 256) {
      int nl = e >> 2, c4 = e & 3;
      *(uint4*)(Bs[0] + nl * BP2 + c4 * 8) = *(const uint4*)(src + nl * 32 + c4 * 8);
    }
  }
  __syncthreads();

  // ---------- layer 1: K=288 (9 chgs), M-tiles at +0 and +4 ----------
  {
    f16v a0 = {}, a1 = {};
    for (int chg = 0; chg < 9; ++chg) {
      const int p = chg & 1;
      if (chg + 1 < 9) {
        const _Float16* src = W1p + (size_t)(chg + 1) * 8192 + z * 4096;
        for (int e = tid; e < 512; e += 256) {
          int nl = e >> 2, c4 = e & 3;
          *(uint4*)(Bs[p ^ 1] + nl * BP2 + c4 * 8) = *(const uint4*)(src + nl * 32 + c4 * 8);
        }
      }
#pragma unroll
      for (int s = 0; s < 2; ++s) {
        const int c16 = chg * 2 + s;
        const int kappa = c16 / 6;
        const int icol = (c16 - kappa * 6) * 16;
        h8v bf = *(const h8v*)(Bs[p] + (n0loc + lm) * BP2 + s * 16 + half * 8);
        h8v aa0 = *(const h8v*)(xs + (lm + kappa) * XP2 + icol + half * 8);
        h8v aa1 = *(const h8v*)(xs + (lm + kappa + 4) * XP2 + icol + half * 8);
        a0 = __builtin_amdgcn_mfma_f32_32x32x16_f16(aa0, bf, a0, 0, 0, 0);
        a1 = __builtin_amdgcn_mfma_f32_32x32x16_f16(aa1, bf, a1, 0, 0, 0);
      }
      __syncthreads();
    }
    const float bv = b1[c];
#pragma unroll
    for (int reg = 0; reg < 16; ++reg) {
      int row = (reg & 3) + 8 * (reg >> 2) + 4 * half;
      {
        int t = t0 - 2 + row;                // tile a -> idx row
        float v = (t >= 0 && t < T_LEN) ? fmaxf(a0[reg] + bv, 0.f) : 0.f;
        h1s[row * HP2 + n0loc + lm] = (_Float16)v;
      }
      if (row >= 28) {                       // tile b -> idx row+4 (32..35)
        int t = t0 + 2 + row;
        float v = (t >= 0 && t < T_LEN) ? fmaxf(a1[reg] + bv, 0.f) : 0.f;
        h1s[(row + 4) * HP2 + n0loc + lm] = (_Float16)v;
      }
    }
  }
  {
    const _Float16* src = W2p + z * 4096;    // Bs[0] free after loop barrier
    for (int e = tid; e < 512; e += 256) {
      int nl = e >> 2, c4 = e & 3;
      *(uint4*)(Bs[0] + nl * BP2 + c4 * 8) = *(const uint4*)(src + nl * 32 + c4 * 8);
    }
  }
  __syncthreads();

  // ---------- layer 2: K=96 grouped (3 chgs), M-tiles at +0 and +2 ----------
  {
    f16v a0 = {}, a1 = {};
    for (int chg = 0; chg < 3; ++chg) {
      const int p = chg & 1;
      if (chg + 1 < 3) {
        const _Float16* src = W2p + (size_t)(chg + 1) * 8192 + z * 4096;
        for (int e = tid; e < 512; e += 256) {
          int nl = e >> 2, c4 = e & 3;
          *(uint4*)(Bs[p ^ 1] + nl * BP2 + c4 * 8) = *(const uint4*)(src + nl * 32 + c4 * 8);
        }
      }
#pragma unroll
      for (int s = 0; s < 2; ++s) {
        const int c16 = chg * 2 + s;
        const int kappa = c16 >> 1;
        const int icol = n0loc + (c16 & 1) * 16;   // in-group == N-tile
        h8v bf = *(const h8v*)(Bs[p] + (n0loc + lm) * BP2 + s * 16 + half * 8);
        h8v aa0 = *(const h8v*)(h1s + (lm + kappa) * HP2 + icol + half * 8);
        h8v aa1 = *(const h8v*)(h1s + (lm + kappa + 2) * HP2 + icol + half * 8);
        a0 = __builtin_amdgcn_mfma_f32_32x32x16_f16(aa0, bf, a0, 0, 0, 0);
        a1 = __builtin_amdgcn_mfma_f32_32x32x16_f16(aa1, bf, a1, 0, 0, 0);
      }
      __syncthreads();
    }
    const float bv = b2[c];
#pragma unroll
    for (int reg = 0; reg < 16; ++reg) {
      int row = (reg & 3) + 8 * (reg >> 2) + 4 * half;
      {
        int t = t0 - 1 + row;                // tile a -> idx row
        float v = (t >= 0 && t < T_LEN) ? fmaxf(a0[reg] + bv, 0.f) : 0.f;
        h2s[row * HP2 + n0loc + lm] = (_Float16)v;
      }
      if (row >= 30) {                       // tile b -> idx row+2 (32..33)
        int t = t0 + 1 + row;
        float v = (t >= 0 && t < T_LEN) ? fmaxf(a1[reg] + bv, 0.f) : 0.f;
        h2s[(row + 2) * HP2 + n0loc + lm] = (_Float16)v;
      }
    }
  }
  {
    const _Float16* src = W3p + z * 4096;
    for (int e = tid; e < 512; e += 256) {
      int nl = e >> 2, c4 = e & 3;
      *(uint4*)(Bs[0] + nl * BP2 + c4 * 8) = *(const uint4*)(src + nl * 32 + c4 * 8);
    }
  }
  __syncthreads();

  // ---------- layer 3: K=96 grouped (3 chgs), one M-tile ----------
  {
    f16v a0 = {};
    for (int chg = 0; chg < 3; ++chg) {
      const int p = chg & 1;
      if (chg + 1 < 3) {
        const _Float16* src = W3p + (size_t)(chg + 1) * 8192 + z * 4096;
        for (int e = tid; e < 512; e += 256) {
          int nl = e >> 2, c4 = e & 3;
          *(uint4*)(Bs[p ^ 1] + nl * BP2 + c4 * 8) = *(const uint4*)(src + nl * 32 + c4 * 8);
        }
      }
#pragma unroll
      for (int s = 0; s < 2; ++s) {
        const int c16 = chg * 2 + s;
        const int kappa = c16 >> 1;
        const int icol = n0loc + (c16 & 1) * 16;
        h8v bf = *(const h8v*)(Bs[p] + (n0loc + lm) * BP2 + s * 16 + half * 8);
        h8v aa = *(const h8v*)(h2s + (lm + kappa) * HP2 + icol + half * 8);
        a0 = __builtin_amdgcn_mfma_f32_32x32x16_f16(aa, bf, a0, 0, 0, 0);
      }
      __syncthreads();
    }
    const float bv = b3[c];
#pragma unroll
    for (int reg = 0; reg < 16; ++reg) {
      int row = (reg & 3) + 8 * (reg >> 2) + 4 * half;
      int t = t0 + row;
      if (t < T_LEN)
        out[(size_t)(b * T_LEN + t) * CONV_CH + c] =
            __float2bfloat16(fmaxf(a0[reg] + bv, 0.f));
    }
  }
}

// ============ conv4 as MFMA GEMM, K-split x2, M-tile 32: 512 blocks (2/CU) ====
// Middle point of the round-7/round-8 tradeoff: keeps 2 blocks/CU (round-8's
// 1/CU exposed barrier drains) while halving P-partial HBM traffic vs the
// 4-way split (round 7). M=32 (t0=mb*32), N=256, 4 waves x 2 accs
// (n = w*64 + {0,32}); ks halves K: k0 = ks*384 + ch*32 + s*16, 12 chunks.
#define AP4 264
#define BPITCH 40
#define PSTRIDE 1792000
__global__ __launch_bounds__(256) void k_conv4m(
    const __hip_bfloat16* __restrict__ h3, const __hip_bfloat16* __restrict__ Wc,
    const float* __restrict__ bias, float* __restrict__ Pbase) {
  const int mb = blockIdx.x, b = blockIdx.y, ks = blockIdx.z;
  float* __restrict__ P = Pbase + (size_t)ks * PSTRIDE;
  const int t0 = mb * 32;
  const int tid = threadIdx.x;
  const int w = tid >> 6, lane = tid & 63;
  const int lm = lane & 31, half = lane >> 5;

  __shared__ short h3s[34 * AP4];            // rows t0-1 .. t0+32
  __shared__ short Bs[2][256 * BPITCH];

  const ushort* h3u = (const ushort*)h3;
  for (int g = tid; g < 34 * 64; g += 256) {
    int rr = g >> 6, c4 = g & 63;
    int t = t0 + rr - 1;
    uint2 v = make_uint2(0u, 0u);
    if (t >= 0 && t < T_LEN)
      v = *(const uint2*)(h3u + (b * T_LEN + t) * CONV_CH + c4 * 4);
    *(uint2*)(h3s + rr * AP4 + c4 * 4) = v;
  }

  const ushort* Wu = (const ushort*)Wc + (size_t)(ks * 12) * 8192;
#pragma unroll
  for (int it = 0; it < 4; ++it) {
    int idx = (it * 256 + tid) * 8;
    uint4 v = *(const uint4*)(Wu + idx);
    int n = idx >> 5, kloc = idx & 31;
    *(uint4*)(Bs[0] + n * BPITCH + kloc) = v;
  }
  __syncthreads();

  f16v acc0 = {}, acc1 = {};

  for (int ch = 0; ch < 12; ++ch) {
    const int p = ch & 1;
    if (ch < 11) {
      const ushort* src = Wu + (size_t)(ch + 1) * 8192;
#pragma unroll
      for (int it = 0; it < 4; ++it) {
        int idx = (it * 256 + tid) * 8;
        uint4 v = *(const uint4*)(src + idx);
        int n = idx >> 5, kloc = idx & 31;
        *(uint4*)(Bs[p ^ 1] + n * BPITCH + kloc) = v;
      }
    }
#pragma unroll
    for (int s = 0; s < 2; ++s) {
      int k0 = ks * 384 + ch * 32 + s * 16;
      int kappa = k0 >> 8, i0 = k0 & 255;
      s8v a = *(const s8v*)(h3s + (lm + kappa) * AP4 + i0 + half * 8);
      const short* bp = Bs[p] + (w * 64 + lm) * BPITCH + s * 16 + half * 8;
      s8v b0 = *(const s8v*)(bp);
      s8v b1 = *(const s8v*)(bp + 32 * BPITCH);
      acc0 = __builtin_amdgcn_mfma_f32_32x32x16_bf16(a, b0, acc0, 0, 0, 0);
      acc1 = __builtin_amdgcn_mfma_f32_32x32x16_bf16(a, b1, acc1, 0, 0, 0);
    }
    __syncthreads();
  }

#pragma unroll
  for (int nt = 0; nt < 2; ++nt) {
    int c = w * 64 + nt * 32 + lm;
    if (c >= CCEP_N) continue;
    float bq = 0.f;
    if (ks == 0) {
      float invq = 1.f / (float)((c < 111) ? (111 - c) : (c - 110));
      bq = bias[c] * invq;
    }
    const f16v* A = nt ? &acc1 : &acc0;
#pragma unroll
    for (int reg = 0; reg < 16; ++reg) {
      int row = (reg & 3) + 8 * (reg >> 2) + 4 * half;
      int t = t0 + row;
      if (t < T_LEN)
        P[(size_t)(b * T_LEN + t) * 224 + c] = (*A)[reg] + bq;
    }
  }
}

// ============================ fused FFT kernel (2 frames/block) ===============
// Frames tA=2u, tB=2u+1. Two packed forward FFTs (c + i*fr per frame); S_A, S_B
// Hermitian -> ONE inverse: Z = S_A + i*S_B, IFFT(Z) = C_A + i*C_B (both real).
// Odd rows stored directly; even-row contributions spilled to sbl/sbr; no atomics.
__device__ __forceinline__ float2 cmul(float2 a, float2 b) {
  return make_float2(fmaf(a.x, b.x, -(a.y * b.y)), fmaf(a.x, b.y, a.y * b.x));
}
__device__ __forceinline__ float2 cadd(float2 a, float2 b) { return make_float2(a.x + b.x, a.y + b.y); }
__device__ __forceinline__ float2 csub(float2 a, float2 b) { return make_float2(a.x - b.x, a.y - b.y); }

#define LIDX(i) ((i) + ((i) >> 2))

template <int Q, int OFF>
__device__ __forceinline__ void fwd_stage2(float2* __restrict__ A,
    float2* __restrict__ B, const float2* __restrict__ Tw, int j) {
  const int pos = j & (Q - 1);
  const int base = ((j - pos) << 2) + pos;
  float2 e1 = Tw[OFF + pos], e2 = Tw[OFF + Q + pos], e3 = Tw[OFF + 2 * Q + pos];
  const float2 w1 = make_float2(e1.x, -e1.y);
  const float2 w2 = make_float2(e2.x, -e2.y);
  const float2 w3 = make_float2(e3.x, -e3.y);
#pragma unroll
  for (int arr = 0; arr < 2; ++arr) {
    float2* X = arr ? B : A;
    float2 a = X[LIDX(base)], b = X[LIDX(base + Q)];
    float2 cc = X[LIDX(base + 2 * Q)], d = X[LIDX(base + 3 * Q)];
    float2 t0 = cadd(a, cc), t1 = csub(a, cc), t2 = cadd(b, d), bd = csub(b, d);
    float2 t3 = make_float2(bd.y, -bd.x);
    X[LIDX(base)]         = cadd(t0, t2);
    X[LIDX(base + Q)]     = cmul(cadd(t1, t3), w1);
    X[LIDX(base + 2 * Q)] = cmul(csub(t0, t2), w2);
    X[LIDX(base + 3 * Q)] = cmul(csub(t1, t3), w3);
  }
}

template <int Q, int OFF>
__device__ __forceinline__ void inv_stage_t(float2* __restrict__ X,
    const float2* __restrict__ Tw, int j) {
  const int pos = j & (Q - 1);
  const int base = ((j - pos) << 2) + pos;
  const float2 w1 = Tw[OFF + pos];
  const float2 w2 = Tw[OFF + Q + pos];
  const float2 w3 = Tw[OFF + 2 * Q + pos];
  float2 a = X[LIDX(base)];
  float2 b = cmul(X[LIDX(base + Q)], w1);
  float2 cc = cmul(X[LIDX(base + 2 * Q)], w2);
  float2 d = cmul(X[LIDX(base + 3 * Q)], w3);
  float2 t0 = cadd(a, cc), t1 = csub(a, cc), t2 = cadd(b, d), bd = csub(b, d);
  float2 t3 = make_float2(-bd.y, bd.x);
  X[LIDX(base)]         = cadd(t0, t2);
  X[LIDX(base + Q)]     = cadd(t1, t3);
  X[LIDX(base + 2 * Q)] = csub(t0, t2);
  X[LIDX(base + 3 * Q)] = csub(t1, t3);
}

__device__ __forceinline__ int rev4d(int v) {
  return ((v & 3) << 6) | (((v >> 2) & 3) << 4) | (((v >> 4) & 3) << 2) | ((v >> 6) & 3);
}

// grid (500, 8)
__global__ __launch_bounds__(256) void k_fft(const float* __restrict__ Pb,
    const float* __restrict__ z, const float2* __restrict__ twg,
    const float* __restrict__ wing, float* __restrict__ out,
    float* __restrict__ sbl, float* __restrict__ sbr) {
  const int u = blockIdx.x, b = blockIdx.y;
  const int tA = 2 * u, tB = tA + 1;
  const int btA = b * T_LEN + tA, btB = btA + 1;
  const int j = threadIdx.x;
  __shared__ float2 WlA[1280];
  __shared__ float2 WlB[1280];
  __shared__ float2 Tws[1020];
  for (int e = j; e < 1020; e += 256) Tws[e] = twg[e];

  const float* zb = z + b * 256000;
  float f0A = 0.f, fS, f1B = 0.f;
  {
    int zi0 = tA * 256 + j - 255;
    f0A = (zi0 >= 0) ? zb[zi0] : 0.f;
    fS = zb[tA * 256 + j + 1];
    int zi2 = tB * 256 + j + 1;
    f1B = (zi2 < 256000) ? zb[zi2] : 0.f;
  }
  float c1A = 0.f, c2A = 0.f, c1B = 0.f, c2B = 0.f;
  if (j >= 145) {
    int mA = btA * 224 + (j - 145), mB = btB * 224 + (j - 145);
    c1A = Pb[mA] + Pb[mA + PSTRIDE];
    c1B = Pb[mB] + Pb[mB + PSTRIDE];
  }
  if (j < 111) {
    int mA = btA * 224 + (j + 111), mB = btB * 224 + (j + 111);
    c2A = Pb[mA] + Pb[mA + PSTRIDE];
    c2B = Pb[mB] + Pb[mB + PSTRIDE];
  }
  __syncthreads();

  {
    float2 e1 = Tws[j], e2 = Tws[256 + j], e3 = Tws[512 + j];
    const float2 w1 = make_float2(e1.x, -e1.y);
    const float2 w2 = make_float2(e2.x, -e2.y);
    const float2 w3 = make_float2(e3.x, -e3.y);
    {
      float2 t0 = make_float2(c2A, f0A);
      float2 t1 = make_float2(-c2A, f0A);
      float2 t2 = make_float2(c1A, fS);
      float2 t3 = make_float2(fS, -c1A);
      WlA[LIDX(j)]       = cadd(t0, t2);
      WlA[LIDX(j + 256)] = cmul(cadd(t1, t3), w1);
      WlA[LIDX(j + 512)] = cmul(csub(t0, t2), w2);
      WlA[LIDX(j + 768)] = cmul(csub(t1, t3), w3);
    }
    {
      float2 t0 = make_float2(c2B, fS);
      float2 t1 = make_float2(-c2B, fS);
      float2 t2 = make_float2(c1B, f1B);
      float2 t3 = make_float2(f1B, -c1B);
      WlB[LIDX(j)]       = cadd(t0, t2);
      WlB[LIDX(j + 256)] = cmul(cadd(t1, t3), w1);
      WlB[LIDX(j + 512)] = cmul(csub(t0, t2), w2);
      WlB[LIDX(j + 768)] = cmul(csub(t1, t3), w3);
    }
  }
  __syncthreads();

  fwd_stage2<64, 768>(WlA, WlB, Tws, j);  __syncthreads();
  fwd_stage2<16, 960>(WlA, WlB, Tws, j);  __syncthreads();
  fwd_stage2<4, 1008>(WlA, WlB, Tws, j);  __syncthreads();

  const int base = 4 * j;
  float2 XA[4], XB[4];
  {
    float2 u0 = WlA[LIDX(base)], u1 = WlA[LIDX(base + 1)];
    float2 u2 = WlA[LIDX(base + 2)], u3 = WlA[LIDX(base + 3)];
    float2 t0 = cadd(u0, u2), t1 = csub(u0, u2), t2 = cadd(u1, u3), bd = csub(u1, u3);
    float2 t3 = make_float2(bd.y, -bd.x);
    XA[0] = cadd(t0, t2); XA[1] = cadd(t1, t3); XA[2] = csub(t0, t2); XA[3] = csub(t1, t3);
  }
  {
    float2 u0 = WlB[LIDX(base)], u1 = WlB[LIDX(base + 1)];
    float2 u2 = WlB[LIDX(base + 2)], u3 = WlB[LIDX(base + 3)];
    float2 t0 = cadd(u0, u2), t1 = csub(u0, u2), t2 = cadd(u1, u3), bd = csub(u1, u3);
    float2 t3 = make_float2(bd.y, -bd.x);
    XB[0] = cadd(t0, t2); XB[1] = cadd(t1, t3); XB[2] = csub(t0, t2); XB[3] = csub(t1, t3);
  }
#pragma unroll
  for (int q = 0; q < 4; ++q) { WlA[LIDX(base + q)] = XA[q]; WlB[LIDX(base + q)] = XB[q]; }
  __syncthreads();

  const int r0 = rev4d(j);
  const bool self0 = (r0 == 0);
  const int jp = self0 ? 0 : rev4d((256 - r0) & 255);
  float2 PA[4], PB[4];
#pragma unroll
  for (int q = 0; q < 4; ++q) { PA[q] = WlA[LIDX(4 * jp + q)]; PB[q] = WlB[LIDX(4 * jp + q)]; }
  float2 Z[4];
#pragma unroll
  for (int q = 0; q < 4; ++q) {
    float2 SA, SB;
    {
      float2 A = XA[q];
      float2 Bc = self0 ? PA[(4 - q) & 3] : PA[3 - q];
      float2 Y = make_float2(0.5f * (A.x + Bc.x), 0.5f * (A.y - Bc.y));
      float2 F = make_float2(0.5f * (A.y + Bc.y), -0.5f * (A.x - Bc.x));
      float mag = __expf(Y.x * 2.30258509299404568402f);
      float sy, cy;
      __sincosf(Y.y, &sy, &cy);
      float gr = mag * cy, gi = mag * sy;
      SA = make_float2(fmaf(F.x, gr, F.y * gi), fmaf(F.x, gi, -(F.y * gr)));
    }
    {
      float2 A = XB[q];
      float2 Bc = self0 ? PB[(4 - q) & 3] : PB[3 - q];
      float2 Y = make_float2(0.5f * (A.x + Bc.x), 0.5f * (A.y - Bc.y));
      float2 F = make_float2(0.5f * (A.y + Bc.y), -0.5f * (A.x - Bc.x));
      float mag = __expf(Y.x * 2.30258509299404568402f);
      float sy, cy;
      __sincosf(Y.y, &sy, &cy);
      float gr = mag * cy, gi = mag * sy;
      SB = make_float2(fmaf(F.x, gr, F.y * gi), fmaf(F.x, gi, -(F.y * gr)));
    }
    Z[q] = make_float2(SA.x - SB.y, SA.y + SB.x);   // S_A + i*S_B
  }
  __syncthreads();

  {
    float2 t0 = cadd(Z[0], Z[2]), t1 = csub(Z[0], Z[2]), t2 = cadd(Z[1], Z[3]), bd = csub(Z[1], Z[3]);
    float2 t3 = make_float2(-bd.y, bd.x);
    WlA[LIDX(base)]     = cadd(t0, t2);
    WlA[LIDX(base + 1)] = cadd(t1, t3);
    WlA[LIDX(base + 2)] = csub(t0, t2);
    WlA[LIDX(base + 3)] = csub(t1, t3);
  }
  __syncthreads();

  inv_stage_t<4, 1008>(WlA, Tws, j);  __syncthreads();
  inv_stage_t<16, 960>(WlA, Tws, j);  __syncthreads();
  inv_stage_t<64, 768>(WlA, Tws, j);  __syncthreads();

  {
    float2 w1 = Tws[j], w2 = Tws[256 + j], w3 = Tws[512 + j];
    float2 a = WlA[LIDX(j)];
    float2 bb = cmul(WlA[LIDX(j + 256)], w1);
    float2 cc = cmul(WlA[LIDX(j + 512)], w2);
    float2 d = cmul(WlA[LIDX(j + 768)], w3);
    float2 t0 = cadd(a, cc), t1 = csub(a, cc), t2 = cadd(bb, d), bd = csub(bb, d);
    float2 t3 = make_float2(-bd.y, bd.x);
    float2 Cj    = cadd(t0, t2);   // C[j]     -> corr n1 = 511-j (r-part)
    float2 Cj256 = cadd(t1, t3);   // C[j+256] -> corr n2 = 255-j (l-part)
    int n1 = 511 - j, n2 = 255 - j;
    float wn1 = wing[n1], wn2 = wing[n2];
    float vA_l = Cj256.x * wn2;                 // even row tA contribution (l)
    float vAB  = Cj.x * wn1 + Cj256.y * wn2;    // odd row tB: A.r + B.l (owned)
    float vB_r = Cj.y * wn1;                    // even row tB+1 contribution (r)
    out[(b * T_LEN + tB) * 256 + n2] = vAB;
    int su = (b * 500 + u) * 256 + n2;
    sbl[su] = vA_l;
    sbr[su] = vB_r;
  }
}

// ---- even rows: out[b, 2u, n] = l(2u) + r(2u-1 mod 1000) ---------------------
__global__ __launch_bounds__(256) void k_even(const float* __restrict__ sbl,
    const float* __restrict__ sbr, float* __restrict__ out) {
  int idx = blockIdx.x * 256 + threadIdx.x;   // 1,024,000
  int n = idx & 255;
  int bu = idx >> 8;                          // b*500 + u
  int u = bu % 500, b = bu / 500;
  int up = (u == 0) ? 499 : u - 1;
  out[(b * T_LEN + 2 * u) * 256 + n] = sbl[idx] + sbr[(b * 500 + up) * 256 + n];
}

extern "C" void kernel_launch(void* const* d_in, const int* in_sizes, int n_in,
                              void* d_out, int out_size, void* d_ws, size_t ws_size,
                              hipStream_t stream) {
  const float* x  = (const float*)d_in[0];
  const float* z  = (const float*)d_in[1];
  const float* W1 = (const float*)d_in[2];
  const float* b1 = (const float*)d_in[3];
  const float* W2 = (const float*)d_in[4];
  const float* b2 = (const float*)d_in[5];
  const float* W3 = (const float*)d_in[6];
  const float* b3 = (const float*)d_in[7];
  const float* W4 = (const float*)d_in[8];
  const float* b4 = (const float*)d_in[9];

  float* ws   = (float*)d_ws;
  __hip_bfloat16* h3bf = (__hip_bfloat16*)ws;              // 1,024,000 f32 slots
  float* Pb   = ws + 1024000;            // 2 x 1,792,000 = 3,584,000
  float* sbl  = ws + 8192000;            // 1,024,000
  float* sbr  = ws + 9216000;            // 1,024,000
  _Float16* W1p = (_Float16*)(ws + 10240000);              // 73,728 halves
  _Float16* W2p = (_Float16*)(ws + 10301440);              // 24,576 halves
  _Float16* W3p = (_Float16*)(ws + 10326016);              // 24,576 halves
  __hip_bfloat16* Wc = (__hip_bfloat16*)(ws + 10350592);   // 98,304 f32 slots
  float2* twTab = (float2*)(ws + 10448896);                // 1020 float2
  float* winTab = ws + 10450944;                           // 512
  float* out = (float*)d_out;

  dim3 blk(256);
  k_prep<<<480, blk, 0, stream>>>(W1, W2, W3, W1p, W2p, W3p);

  dim3 gc(32, B_N, 3);             // z 0,1: conv planes; z 2: table prep
  k_convfused<<<gc, blk, 0, stream>>>(x, W1p, b1, W2p, b2, W3p, b3, h3bf,
                                      W4, Wc, twTab, winTab);
  dim3 g4(32, B_N, 2);             // K-split x2, M-tile 32 (2 blocks/CU)
  k_conv4m<<<g4, blk, 0, stream>>>(h3bf, Wc, b4, Pb);
  dim3 gf(T_LEN / 2, B_N);         // (500, 8)
  k_fft<<<gf, blk, 0, stream>>>(Pb, z, twTab, winTab, out, sbl, sbr);
  k_even<<<4000, blk, 0, stream>>>(sbl, sbr, out);
}

// Round 11
// 146.678 us; speedup vs baseline: 1.0497x; 1.0092x over previous
//
#include <hip/hip_runtime.h>
#include <hip/hip_bf16.h>

#define T_LEN 1000
#define B_N 8
#define IN_CH 80
#define CONV_CH 256
#define CCEP_N 222

typedef short s8v __attribute__((ext_vector_type(8)));      // 8 bf16 (4 VGPRs)
typedef _Float16 h8v __attribute__((ext_vector_type(8)));   // 8 fp16 (4 VGPRs)
typedef float f16v __attribute__((ext_vector_type(16)));    // MFMA 32x32 acc

#define TWO_PI 6.28318530717958647692f

// ===================== prep kernel: conv1-3 weights only ======================
// [0,288): W1p [9][256][32] fp16, k = chg*32+kloc in [0,288), kappa=k/96, i=k%96
//          (i>=80 zero-padded);
// [288,384): W2p [3][256][32], k in [0,96), kappa=k>>5, iloc=k&31;
// [384,480): W3p same.
__global__ __launch_bounds__(256) void k_prep(
    const float* __restrict__ W1, const float* __restrict__ W2,
    const float* __restrict__ W3,
    _Float16* __restrict__ W1p, _Float16* __restrict__ W2p,
    _Float16* __restrict__ W3p) {
  const int bid = blockIdx.x, tid = threadIdx.x;
  if (bid < 288) {
    int e = bid * 256 + tid;                 // 73728 = 9*8192
    int kloc = e & 31, n = (e >> 5) & 255, chg = e >> 13;
    int k = chg * 32 + kloc;
    int kappa = k / 96, i = k - kappa * 96;
    W1p[e] = (i < IN_CH) ? (_Float16)W1[n * 240 + i * 3 + kappa] : (_Float16)0.f;
  } else if (bid < 384) {
    int e = (bid - 288) * 256 + tid;         // 24576 = 3*8192
    int kloc = e & 31, n = (e >> 5) & 255, chg = e >> 13;
    int k = chg * 32 + kloc;
    int kappa = k >> 5, iloc = k & 31;
    W2p[e] = (_Float16)W2[n * 96 + iloc * 3 + kappa];
  } else {
    int e = (bid - 384) * 256 + tid;
    int kloc = e & 31, n = (e >> 5) & 255, chg = e >> 13;
    int k = chg * 32 + kloc;
    int kappa = k >> 5, iloc = k & 31;
    W3p[e] = (_Float16)W3[n * 96 + iloc * 3 + kappa];
  }
}

// ===== conv1-3 FULLY FUSED as MFMA fp16 GEMMs, h1/h2 in LDS ===================
// grid (32, 8, 3). z in {0,1}: conv planes (block = 32 t x 128 ch). z == 2:
// table-prep plane (256 blocks): Wc (conv4 bf16 weights, /quef fused) +
// twiddle + window tables. No shared state between planes; consumers
// (k_conv4m, k_fft) launch later on the same stream.
// Conv: halo via overlapping M-tiles: L1 computes h1 rows t0-2..t0+33 (tiles
// at offset 0 and +4, tile-b stores only row>=28); L2 computes h2 rows
// t0-1..t0+32 (offsets 0 and +2, tile-b stores row>=30); L3 one tile.
// Rows outside [0,T) zeroed at store (reference zero-pads each layer).
// x staged fp32->fp16 in-kernel. B double-buffered per 32-k chunk (pitch 48).
#define XP2 112   // xs pitch (halves): 224B, 4-way max bank aliasing
#define HP2 144   // h1s/h2s pitch: 288B, 4-way
#define BP2 48    // Bs pitch: 96B, 4-way

__global__ __launch_bounds__(256) void k_convfused(
    const float* __restrict__ x,
    const _Float16* __restrict__ W1p, const float* __restrict__ b1,
    const _Float16* __restrict__ W2p, const float* __restrict__ b2,
    const _Float16* __restrict__ W3p, const float* __restrict__ b3,
    __hip_bfloat16* __restrict__ out,
    const float* __restrict__ W4, __hip_bfloat16* __restrict__ Wc,
    float2* __restrict__ twTab, float* __restrict__ winTab) {
  const int tid = threadIdx.x;

  if (blockIdx.z == 2) {
    // ---- table-prep plane: Wc (196608) + twiddle (1020) + window (512) ----
    int blk = blockIdx.y * 32 + blockIdx.x;        // 0..255
    for (int e = blk * 256 + tid; e < 196608 + 1532; e += 65536) {
      if (e < 196608) {
        int kloc = e & 31, n = (e >> 5) & 255, chg = e >> 13;
        int kp = chg * 32 + kloc;
        int kappa = kp >> 8, i = kp & 255;
        float v = 0.f;
        if (n < CCEP_N) {
          float invq = 1.f / (float)((n < 111) ? (111 - n) : (n - 110));
          v = W4[n * 768 + i * 3 + kappa] * invq;
        }
        Wc[e] = __float2bfloat16(v);
      } else {
        int e2 = e - 196608;
        if (e2 < 1020) {
          int Q, off;
          if (e2 < 768)       { Q = 256; off = 0; }
          else if (e2 < 960)  { Q = 64;  off = 768; }
          else if (e2 < 1008) { Q = 16;  off = 960; }
          else                { Q = 4;   off = 1008; }
          int rem = e2 - off;
          int r = rem / Q, pos = rem - r * Q;
          float ang = (TWO_PI * (float)((r + 1) * pos)) / (float)(4 * Q);
          float s, c;
          sincosf(ang, &s, &c);
          twTab[e2] = make_float2(c, s);
        } else if (e2 < 1532) {
          int n = e2 - 1020;
          winTab[n] = (0.5f - 0.5f * cosf(TWO_PI * (float)n / 512.f)) * (1.f / 1024.f);
        }
      }
    }
    return;
  }

  const int mb = blockIdx.x, b = blockIdx.y, z = blockIdx.z;
  const int t0 = mb * 32;
  const int w = tid >> 6, lane = tid & 63;
  const int lm = lane & 31, half = lane >> 5;
  const int n0loc = w * 32;                  // wave's N-tile within block's 128
  const int c = z * 128 + n0loc + lm;        // global out channel

  __shared__ _Float16 xs[38 * XP2];          // rows t0-3 .. t0+34
  __shared__ _Float16 h1s[36 * HP2];         // idx = t-(t0-2), 0..35
  __shared__ _Float16 h2s[34 * HP2];         // idx = t-(t0-1), 0..33
  __shared__ _Float16 Bs[2][128 * BP2];

  // ---- stage x (fp32 -> fp16), zero-pad t outside [0,T) and ch >= 80 ----
  for (int e = tid; e < 38 * 96; e += 256) {
    int rr = e / 96, cc = e - rr * 96;
    int t = t0 - 3 + rr;
    float v = (cc < IN_CH && t >= 0 && t < T_LEN)
                  ? x[(b * T_LEN + t) * IN_CH + cc] : 0.f;
    xs[rr * XP2 + cc] = (_Float16)v;
  }
  {
    const _Float16* src = W1p + z * 4096;    // chg 0, this block's 128 n
    for (int e = tid; e < 512; e += 256) {
      int nl = e >> 2, c4 = e & 3;
      *(uint4*)(Bs[0] + nl * BP2 + c4 * 8) = *(const uint4*)(src + nl * 32 + c4 * 8);
    }
  }
  __syncthreads();

  // ---------- layer 1: K=288 (9 chgs), M-tiles at +0 and +4 ----------
  {
    f16v a0 = {}, a1 = {};
    for (int chg = 0; chg < 9; ++chg) {
      const int p = chg & 1;
      if (chg + 1 < 9) {
        const _Float16* src = W1p + (size_t)(chg + 1) * 8192 + z * 4096;
        for (int e = tid; e < 512; e += 256) {
          int nl = e >> 2, c4 = e & 3;
          *(uint4*)(Bs[p ^ 1] + nl * BP2 + c4 * 8) = *(const uint4*)(src + nl * 32 + c4 * 8);
        }
      }
#pragma unroll
      for (int s = 0; s < 2; ++s) {
        const int c16 = chg * 2 + s;
        const int kappa = c16 / 6;
        const int icol = (c16 - kappa * 6) * 16;
        h8v bf = *(const h8v*)(Bs[p] + (n0loc + lm) * BP2 + s * 16 + half * 8);
        h8v aa0 = *(const h8v*)(xs + (lm + kappa) * XP2 + icol + half * 8);
        h8v aa1 = *(const h8v*)(xs + (lm + kappa + 4) * XP2 + icol + half * 8);
        a0 = __builtin_amdgcn_mfma_f32_32x32x16_f16(aa0, bf, a0, 0, 0, 0);
        a1 = __builtin_amdgcn_mfma_f32_32x32x16_f16(aa1, bf, a1, 0, 0, 0);
      }
      __syncthreads();
    }
    const float bv = b1[c];
#pragma unroll
    for (int reg = 0; reg < 16; ++reg) {
      int row = (reg & 3) + 8 * (reg >> 2) + 4 * half;
      {
        int t = t0 - 2 + row;                // tile a -> idx row
        float v = (t >= 0 && t < T_LEN) ? fmaxf(a0[reg] + bv, 0.f) : 0.f;
        h1s[row * HP2 + n0loc + lm] = (_Float16)v;
      }
      if (row >= 28) {                       // tile b -> idx row+4 (32..35)
        int t = t0 + 2 + row;
        float v = (t >= 0 && t < T_LEN) ? fmaxf(a1[reg] + bv, 0.f) : 0.f;
        h1s[(row + 4) * HP2 + n0loc + lm] = (_Float16)v;
      }
    }
  }
  {
    const _Float16* src = W2p + z * 4096;    // Bs[0] free after loop barrier
    for (int e = tid; e < 512; e += 256) {
      int nl = e >> 2, c4 = e & 3;
      *(uint4*)(Bs[0] + nl * BP2 + c4 * 8) = *(const uint4*)(src + nl * 32 + c4 * 8);
    }
  }
  __syncthreads();

  // ---------- layer 2: K=96 grouped (3 chgs), M-tiles at +0 and +2 ----------
  {
    f16v a0 = {}, a1 = {};
    for (int chg = 0; chg < 3; ++chg) {
      const int p = chg & 1;
      if (chg + 1 < 3) {
        const _Float16* src = W2p + (size_t)(chg + 1) * 8192 + z * 4096;
        for (int e = tid; e < 512; e += 256) {
          int nl = e >> 2, c4 = e & 3;
          *(uint4*)(Bs[p ^ 1] + nl * BP2 + c4 * 8) = *(const uint4*)(src + nl * 32 + c4 * 8);
        }
      }
#pragma unroll
      for (int s = 0; s < 2; ++s) {
        const int c16 = chg * 2 + s;
        const int kappa = c16 >> 1;
        const int icol = n0loc + (c16 & 1) * 16;   // in-group == N-tile
        h8v bf = *(const h8v*)(Bs[p] + (n0loc + lm) * BP2 + s * 16 + half * 8);
        h8v aa0 = *(const h8v*)(h1s + (lm + kappa) * HP2 + icol + half * 8);
        h8v aa1 = *(const h8v*)(h1s + (lm + kappa + 2) * HP2 + icol + half * 8);
        a0 = __builtin_amdgcn_mfma_f32_32x32x16_f16(aa0, bf, a0, 0, 0, 0);
        a1 = __builtin_amdgcn_mfma_f32_32x32x16_f16(aa1, bf, a1, 0, 0, 0);
      }
      __syncthreads();
    }
    const float bv = b2[c];
#pragma unroll
    for (int reg = 0; reg < 16; ++reg) {
      int row = (reg & 3) + 8 * (reg >> 2) + 4 * half;
      {
        int t = t0 - 1 + row;                // tile a -> idx row
        float v = (t >= 0 && t < T_LEN) ? fmaxf(a0[reg] + bv, 0.f) : 0.f;
        h2s[row * HP2 + n0loc + lm] = (_Float16)v;
      }
      if (row >= 30) {                       // tile b -> idx row+2 (32..33)
        int t = t0 + 1 + row;
        float v = (t >= 0 && t < T_LEN) ? fmaxf(a1[reg] + bv, 0.f) : 0.f;
        h2s[(row + 2) * HP2 + n0loc + lm] = (_Float16)v;
      }
    }
  }
  {
    const _Float16* src = W3p + z * 4096;
    for (int e = tid; e < 512; e += 256) {
      int nl = e >> 2, c4 = e & 3;
      *(uint4*)(Bs[0] + nl * BP2 + c4 * 8) = *(const uint4*)(src + nl * 32 + c4 * 8);
    }
  }
  __syncthreads();

  // ---------- layer 3: K=96 grouped (3 chgs), one M-tile ----------
  {
    f16v a0 = {};
    for (int chg = 0; chg < 3; ++chg) {
      const int p = chg & 1;
      if (chg + 1 < 3) {
        const _Float16* src = W3p + (size_t)(chg + 1) * 8192 + z * 4096;
        for (int e = tid; e < 512; e += 256) {
          int nl = e >> 2, c4 = e & 3;
          *(uint4*)(Bs[p ^ 1] + nl * BP2 + c4 * 8) = *(const uint4*)(src + nl * 32 + c4 * 8);
        }
      }
#pragma unroll
      for (int s = 0; s < 2; ++s) {
        const int c16 = chg * 2 + s;
        const int kappa = c16 >> 1;
        const int icol = n0loc + (c16 & 1) * 16;
        h8v bf = *(const h8v*)(Bs[p] + (n0loc + lm) * BP2 + s * 16 + half * 8);
        h8v aa = *(const h8v*)(h2s + (lm + kappa) * HP2 + icol + half * 8);
        a0 = __builtin_amdgcn_mfma_f32_32x32x16_f16(aa, bf, a0, 0, 0, 0);
      }
      __syncthreads();
    }
    const float bv = b3[c];
#pragma unroll
    for (int reg = 0; reg < 16; ++reg) {
      int row = (reg & 3) + 8 * (reg >> 2) + 4 * half;
      int t = t0 + row;
      if (t < T_LEN)
        out[(size_t)(b * T_LEN + t) * CONV_CH + c] =
            __float2bfloat16(fmaxf(a0[reg] + bv, 0.f));
    }
  }
}

// ============ conv4 as MFMA GEMM, K-split x2, M-tile 32: 512 blocks (2/CU) ====
// Middle point of the round-7/round-8 tradeoff: keeps 2 blocks/CU (round-8's
// 1/CU exposed barrier drains) while halving P-partial HBM traffic vs the
// 4-way split (round 7). M=32 (t0=mb*32), N=256, 4 waves x 2 accs
// (n = w*64 + {0,32}); ks halves K: k0 = ks*384 + ch*32 + s*16, 12 chunks.
#define AP4 264
#define BPITCH 40
#define PSTRIDE 1792000
__global__ __launch_bounds__(256) void k_conv4m(
    const __hip_bfloat16* __restrict__ h3, const __hip_bfloat16* __restrict__ Wc,
    const float* __restrict__ bias, float* __restrict__ Pbase) {
  const int mb = blockIdx.x, b = blockIdx.y, ks = blockIdx.z;
  float* __restrict__ P = Pbase + (size_t)ks * PSTRIDE;
  const int t0 = mb * 32;
  const int tid = threadIdx.x;
  const int w = tid >> 6, lane = tid & 63;
  const int lm = lane & 31, half = lane >> 5;

  __shared__ short h3s[34 * AP4];            // rows t0-1 .. t0+32
  __shared__ short Bs[2][256 * BPITCH];

  const ushort* h3u = (const ushort*)h3;
  for (int g = tid; g < 34 * 64; g += 256) {
    int rr = g >> 6, c4 = g & 63;
    int t = t0 + rr - 1;
    uint2 v = make_uint2(0u, 0u);
    if (t >= 0 && t < T_LEN)
      v = *(const uint2*)(h3u + (b * T_LEN + t) * CONV_CH + c4 * 4);
    *(uint2*)(h3s + rr * AP4 + c4 * 4) = v;
  }

  const ushort* Wu = (const ushort*)Wc + (size_t)(ks * 12) * 8192;
#pragma unroll
  for (int it = 0; it < 4; ++it) {
    int idx = (it * 256 + tid) * 8;
    uint4 v = *(const uint4*)(Wu + idx);
    int n = idx >> 5, kloc = idx & 31;
    *(uint4*)(Bs[0] + n * BPITCH + kloc) = v;
  }
  __syncthreads();

  f16v acc0 = {}, acc1 = {};

  for (int ch = 0; ch < 12; ++ch) {
    const int p = ch & 1;
    if (ch < 11) {
      const ushort* src = Wu + (size_t)(ch + 1) * 8192;
#pragma unroll
      for (int it = 0; it < 4; ++it) {
        int idx = (it * 256 + tid) * 8;
        uint4 v = *(const uint4*)(src + idx);
        int n = idx >> 5, kloc = idx & 31;
        *(uint4*)(Bs[p ^ 1] + n * BPITCH + kloc) = v;
      }
    }
#pragma unroll
    for (int s = 0; s < 2; ++s) {
      int k0 = ks * 384 + ch * 32 + s * 16;
      int kappa = k0 >> 8, i0 = k0 & 255;
      s8v a = *(const s8v*)(h3s + (lm + kappa) * AP4 + i0 + half * 8);
      const short* bp = Bs[p] + (w * 64 + lm) * BPITCH + s * 16 + half * 8;
      s8v b0 = *(const s8v*)(bp);
      s8v b1 = *(const s8v*)(bp + 32 * BPITCH);
      acc0 = __builtin_amdgcn_mfma_f32_32x32x16_bf16(a, b0, acc0, 0, 0, 0);
      acc1 = __builtin_amdgcn_mfma_f32_32x32x16_bf16(a, b1, acc1, 0, 0, 0);
    }
    __syncthreads();
  }

#pragma unroll
  for (int nt = 0; nt < 2; ++nt) {
    int c = w * 64 + nt * 32 + lm;
    if (c >= CCEP_N) continue;
    float bq = 0.f;
    if (ks == 0) {
      float invq = 1.f / (float)((c < 111) ? (111 - c) : (c - 110));
      bq = bias[c] * invq;
    }
    const f16v* A = nt ? &acc1 : &acc0;
#pragma unroll
    for (int reg = 0; reg < 16; ++reg) {
      int row = (reg & 3) + 8 * (reg >> 2) + 4 * half;
      int t = t0 + row;
      if (t < T_LEN)
        P[(size_t)(b * T_LEN + t) * 224 + c] = (*A)[reg] + bq;
    }
  }
}

// ============================ fused FFT kernel (4 frames/block) ===============
// Block v processes u0=2v then u1=2v+1 (serial, reusing WlA/WlB and the Tws
// staging). Per u: frames tA=2u, tB=2u+1 (same packed fwd/Hermitian/inverse
// structure as before). Even-row resolution: out[2*u1] = sbl[u1] + sbr[u0] is
// computed IN-REGISTER (same thread holds both at the same n2); only sbl[u0]
// and sbr[u1] are exported to global for the cross-block rows out[4v].
__device__ __forceinline__ float2 cmul(float2 a, float2 b) {
  return make_float2(fmaf(a.x, b.x, -(a.y * b.y)), fmaf(a.x, b.y, a.y * b.x));
}
__device__ __forceinline__ float2 cadd(float2 a, float2 b) { return make_float2(a.x + b.x, a.y + b.y); }
__device__ __forceinline__ float2 csub(float2 a, float2 b) { return make_float2(a.x - b.x, a.y - b.y); }

#define LIDX(i) ((i) + ((i) >> 2))

template <int Q, int OFF>
__device__ __forceinline__ void fwd_stage2(float2* __restrict__ A,
    float2* __restrict__ B, const float2* __restrict__ Tw, int j) {
  const int pos = j & (Q - 1);
  const int base = ((j - pos) << 2) + pos;
  float2 e1 = Tw[OFF + pos], e2 = Tw[OFF + Q + pos], e3 = Tw[OFF + 2 * Q + pos];
  const float2 w1 = make_float2(e1.x, -e1.y);
  const float2 w2 = make_float2(e2.x, -e2.y);
  const float2 w3 = make_float2(e3.x, -e3.y);
#pragma unroll
  for (int arr = 0; arr < 2; ++arr) {
    float2* X = arr ? B : A;
    float2 a = X[LIDX(base)], b = X[LIDX(base + Q)];
    float2 cc = X[LIDX(base + 2 * Q)], d = X[LIDX(base + 3 * Q)];
    float2 t0 = cadd(a, cc), t1 = csub(a, cc), t2 = cadd(b, d), bd = csub(b, d);
    float2 t3 = make_float2(bd.y, -bd.x);
    X[LIDX(base)]         = cadd(t0, t2);
    X[LIDX(base + Q)]     = cmul(cadd(t1, t3), w1);
    X[LIDX(base + 2 * Q)] = cmul(csub(t0, t2), w2);
    X[LIDX(base + 3 * Q)] = cmul(csub(t1, t3), w3);
  }
}

template <int Q, int OFF>
__device__ __forceinline__ void inv_stage_t(float2* __restrict__ X,
    const float2* __restrict__ Tw, int j) {
  const int pos = j & (Q - 1);
  const int base = ((j - pos) << 2) + pos;
  const float2 w1 = Tw[OFF + pos];
  const float2 w2 = Tw[OFF + Q + pos];
  const float2 w3 = Tw[OFF + 2 * Q + pos];
  float2 a = X[LIDX(base)];
  float2 b = cmul(X[LIDX(base + Q)], w1);
  float2 cc = cmul(X[LIDX(base + 2 * Q)], w2);
  float2 d = cmul(X[LIDX(base + 3 * Q)], w3);
  float2 t0 = cadd(a, cc), t1 = csub(a, cc), t2 = cadd(b, d), bd = csub(b, d);
  float2 t3 = make_float2(-bd.y, bd.x);
  X[LIDX(base)]         = cadd(t0, t2);
  X[LIDX(base + Q)]     = cadd(t1, t3);
  X[LIDX(base + 2 * Q)] = csub(t0, t2);
  X[LIDX(base + 3 * Q)] = csub(t1, t3);
}

__device__ __forceinline__ int rev4d(int v) {
  return ((v & 3) << 6) | (((v >> 2) & 3) << 4) | (((v >> 4) & 3) << 2) | ((v >> 6) & 3);
}

// grid (250, 8)
__global__ __launch_bounds__(256) void k_fft(const float* __restrict__ Pb,
    const float* __restrict__ z, const float2* __restrict__ twg,
    const float* __restrict__ wing, float* __restrict__ out,
    float* __restrict__ sbl, float* __restrict__ sbr) {
  const int v = blockIdx.x, b = blockIdx.y;
  const int j = threadIdx.x;
  __shared__ float2 WlA[1280];
  __shared__ float2 WlB[1280];
  __shared__ float2 Tws[1020];
  for (int e = j; e < 1020; e += 256) Tws[e] = twg[e];

  const float* zb = z + b * 256000;
  float sbr0 = 0.f;                         // vB_r of u0, consumed by u1's even row

  for (int hu = 0; hu < 2; ++hu) {
    const int u = 2 * v + hu;
    const int tA = 2 * u, tB = tA + 1;
    const int btA = b * T_LEN + tA, btB = btA + 1;

    float f0A = 0.f, fS, f1B = 0.f;
    {
      int zi0 = tA * 256 + j - 255;
      f0A = (zi0 >= 0) ? zb[zi0] : 0.f;
      fS = zb[tA * 256 + j + 1];
      int zi2 = tB * 256 + j + 1;
      f1B = (zi2 < 256000) ? zb[zi2] : 0.f;
    }
    float c1A = 0.f, c2A = 0.f, c1B = 0.f, c2B = 0.f;
    if (j >= 145) {
      int mA = btA * 224 + (j - 145), mB = btB * 224 + (j - 145);
      c1A = Pb[mA] + Pb[mA + PSTRIDE];
      c1B = Pb[mB] + Pb[mB + PSTRIDE];
    }
    if (j < 111) {
      int mA = btA * 224 + (j + 111), mB = btB * 224 + (j + 111);
      c2A = Pb[mA] + Pb[mA + PSTRIDE];
      c2B = Pb[mB] + Pb[mB + PSTRIDE];
    }
    __syncthreads();   // pass 0: Tws ready; pass 1: prior WlA reads complete

    {
      float2 e1 = Tws[j], e2 = Tws[256 + j], e3 = Tws[512 + j];
      const float2 w1 = make_float2(e1.x, -e1.y);
      const float2 w2 = make_float2(e2.x, -e2.y);
      const float2 w3 = make_float2(e3.x, -e3.y);
      {
        float2 t0 = make_float2(c2A, f0A);
        float2 t1 = make_float2(-c2A, f0A);
        float2 t2 = make_float2(c1A, fS);
        float2 t3 = make_float2(fS, -c1A);
        WlA[LIDX(j)]       = cadd(t0, t2);
        WlA[LIDX(j + 256)] = cmul(cadd(t1, t3), w1);
        WlA[LIDX(j + 512)] = cmul(csub(t0, t2), w2);
        WlA[LIDX(j + 768)] = cmul(csub(t1, t3), w3);
      }
      {
        float2 t0 = make_float2(c2B, fS);
        float2 t1 = make_float2(-c2B, fS);
        float2 t2 = make_float2(c1B, f1B);
        float2 t3 = make_float2(f1B, -c1B);
        WlB[LIDX(j)]       = cadd(t0, t2);
        WlB[LIDX(j + 256)] = cmul(cadd(t1, t3), w1);
        WlB[LIDX(j + 512)] = cmul(csub(t0, t2), w2);
        WlB[LIDX(j + 768)] = cmul(csub(t1, t3), w3);
      }
    }
    __syncthreads();

    fwd_stage2<64, 768>(WlA, WlB, Tws, j);  __syncthreads();
    fwd_stage2<16, 960>(WlA, WlB, Tws, j);  __syncthreads();
    fwd_stage2<4, 1008>(WlA, WlB, Tws, j);  __syncthreads();

    const int base = 4 * j;
    float2 XA[4], XB[4];
    {
      float2 u0 = WlA[LIDX(base)], u1 = WlA[LIDX(base + 1)];
      float2 u2 = WlA[LIDX(base + 2)], u3 = WlA[LIDX(base + 3)];
      float2 t0 = cadd(u0, u2), t1 = csub(u0, u2), t2 = cadd(u1, u3), bd = csub(u1, u3);
      float2 t3 = make_float2(bd.y, -bd.x);
      XA[0] = cadd(t0, t2); XA[1] = cadd(t1, t3); XA[2] = csub(t0, t2); XA[3] = csub(t1, t3);
    }
    {
      float2 u0 = WlB[LIDX(base)], u1 = WlB[LIDX(base + 1)];
      float2 u2 = WlB[LIDX(base + 2)], u3 = WlB[LIDX(base + 3)];
      float2 t0 = cadd(u0, u2), t1 = csub(u0, u2), t2 = cadd(u1, u3), bd = csub(u1, u3);
      float2 t3 = make_float2(bd.y, -bd.x);
      XB[0] = cadd(t0, t2); XB[1] = cadd(t1, t3); XB[2] = csub(t0, t2); XB[3] = csub(t1, t3);
    }
#pragma unroll
    for (int q = 0; q < 4; ++q) { WlA[LIDX(base + q)] = XA[q]; WlB[LIDX(base + q)] = XB[q]; }
    __syncthreads();

    const int r0 = rev4d(j);
    const bool self0 = (r0 == 0);
    const int jp = self0 ? 0 : rev4d((256 - r0) & 255);
    float2 PA[4], PB[4];
#pragma unroll
    for (int q = 0; q < 4; ++q) { PA[q] = WlA[LIDX(4 * jp + q)]; PB[q] = WlB[LIDX(4 * jp + q)]; }
    float2 Z[4];
#pragma unroll
    for (int q = 0; q < 4; ++q) {
      float2 SA, SB;
      {
        float2 A = XA[q];
        float2 Bc = self0 ? PA[(4 - q) & 3] : PA[3 - q];
        float2 Y = make_float2(0.5f * (A.x + Bc.x), 0.5f * (A.y - Bc.y));
        float2 F = make_float2(0.5f * (A.y + Bc.y), -0.5f * (A.x - Bc.x));
        float mag = __expf(Y.x * 2.30258509299404568402f);
        float sy, cy;
        __sincosf(Y.y, &sy, &cy);
        float gr = mag * cy, gi = mag * sy;
        SA = make_float2(fmaf(F.x, gr, F.y * gi), fmaf(F.x, gi, -(F.y * gr)));
      }
      {
        float2 A = XB[q];
        float2 Bc = self0 ? PB[(4 - q) & 3] : PB[3 - q];
        float2 Y = make_float2(0.5f * (A.x + Bc.x), 0.5f * (A.y - Bc.y));
        float2 F = make_float2(0.5f * (A.y + Bc.y), -0.5f * (A.x - Bc.x));
        float mag = __expf(Y.x * 2.30258509299404568402f);
        float sy, cy;
        __sincosf(Y.y, &sy, &cy);
        float gr = mag * cy, gi = mag * sy;
        SB = make_float2(fmaf(F.x, gr, F.y * gi), fmaf(F.x, gi, -(F.y * gr)));
      }
      Z[q] = make_float2(SA.x - SB.y, SA.y + SB.x);   // S_A + i*S_B
    }
    __syncthreads();

    {
      float2 t0 = cadd(Z[0], Z[2]), t1 = csub(Z[0], Z[2]), t2 = cadd(Z[1], Z[3]), bd = csub(Z[1], Z[3]);
      float2 t3 = make_float2(-bd.y, bd.x);
      WlA[LIDX(base)]     = cadd(t0, t2);
      WlA[LIDX(base + 1)] = cadd(t1, t3);
      WlA[LIDX(base + 2)] = csub(t0, t2);
      WlA[LIDX(base + 3)] = csub(t1, t3);
    }
    __syncthreads();

    inv_stage_t<4, 1008>(WlA, Tws, j);  __syncthreads();
    inv_stage_t<16, 960>(WlA, Tws, j);  __syncthreads();
    inv_stage_t<64, 768>(WlA, Tws, j);  __syncthreads();

    {
      float2 w1 = Tws[j], w2 = Tws[256 + j], w3 = Tws[512 + j];
      float2 a = WlA[LIDX(j)];
      float2 bb = cmul(WlA[LIDX(j + 256)], w1);
      float2 cc = cmul(WlA[LIDX(j + 512)], w2);
      float2 d = cmul(WlA[LIDX(j + 768)], w3);
      float2 t0 = cadd(a, cc), t1 = csub(a, cc), t2 = cadd(bb, d), bd = csub(bb, d);
      float2 t3 = make_float2(-bd.y, bd.x);
      float2 Cj    = cadd(t0, t2);   // C[j]     -> corr n1 = 511-j (r-part)
      float2 Cj256 = cadd(t1, t3);   // C[j+256] -> corr n2 = 255-j (l-part)
      int n1 = 511 - j, n2 = 255 - j;
      float wn1 = wing[n1], wn2 = wing[n2];
      float vA_l = Cj256.x * wn2;                 // even row tA contribution (l)
      float vAB  = Cj.x * wn1 + Cj256.y * wn2;    // odd row tB: A.r + B.l (owned)
      float vB_r = Cj.y * wn1;                    // even row tB+1 contribution (r)
      out[(b * T_LEN + tB) * 256 + n2] = vAB;
      if (hu == 0) {
        sbr0 = vB_r;                              // consumed by u1's even row
        sbl[(b * 250 + v) * 256 + n2] = vA_l;     // export sbl[u0] for out[4v]
      } else {
        out[(b * T_LEN + tA) * 256 + n2] = vA_l + sbr0;   // out[4v+2] in-block
        sbr[(b * 250 + v) * 256 + n2] = vB_r;     // export sbr[u1] for out[4(v+1)]
      }
    }
  }
}

// ---- remaining even rows: out[b, 4v, n] = sbl[v] + sbr[v-1 mod 250] ----------
__global__ __launch_bounds__(256) void k_even(const float* __restrict__ sbl,
    const float* __restrict__ sbr, float* __restrict__ out) {
  int idx = blockIdx.x * 256 + threadIdx.x;   // 512,000
  int n = idx & 255;
  int bv = idx >> 8;                          // b*250 + v
  int v = bv % 250, b = bv / 250;
  int vp = (v == 0) ? 249 : v - 1;
  out[(b * T_LEN + 4 * v) * 256 + n] = sbl[idx] + sbr[(b * 250 + vp) * 256 + n];
}

extern "C" void kernel_launch(void* const* d_in, const int* in_sizes, int n_in,
                              void* d_out, int out_size, void* d_ws, size_t ws_size,
                              hipStream_t stream) {
  const float* x  = (const float*)d_in[0];
  const float* z  = (const float*)d_in[1];
  const float* W1 = (const float*)d_in[2];
  const float* b1 = (const float*)d_in[3];
  const float* W2 = (const float*)d_in[4];
  const float* b2 = (const float*)d_in[5];
  const float* W3 = (const float*)d_in[6];
  const float* b3 = (const float*)d_in[7];
  const float* W4 = (const float*)d_in[8];
  const float* b4 = (const float*)d_in[9];

  float* ws   = (float*)d_ws;
  __hip_bfloat16* h3bf = (__hip_bfloat16*)ws;              // 1,024,000 f32 slots
  float* Pb   = ws + 1024000;            // 2 x 1,792,000 = 3,584,000
  float* sbl  = ws + 8192000;            // 512,000 used
  float* sbr  = ws + 9216000;            // 512,000 used
  _Float16* W1p = (_Float16*)(ws + 10240000);              // 73,728 halves
  _Float16* W2p = (_Float16*)(ws + 10301440);              // 24,576 halves
  _Float16* W3p = (_Float16*)(ws + 10326016);              // 24,576 halves
  __hip_bfloat16* Wc = (__hip_bfloat16*)(ws + 10350592);   // 98,304 f32 slots
  float2* twTab = (float2*)(ws + 10448896);                // 1020 float2
  float* winTab = ws + 10450944;                           // 512
  float* out = (float*)d_out;

  dim3 blk(256);
  k_prep<<<480, blk, 0, stream>>>(W1, W2, W3, W1p, W2p, W3p);

  dim3 gc(32, B_N, 3);             // z 0,1: conv planes; z 2: table prep
  k_convfused<<<gc, blk, 0, stream>>>(x, W1p, b1, W2p, b2, W3p, b3, h3bf,
                                      W4, Wc, twTab, winTab);
  dim3 g4(32, B_N, 2);             // K-split x2, M-tile 32 (2 blocks/CU)
  k_conv4m<<<g4, blk, 0, stream>>>(h3bf, Wc, b4, Pb);
  dim3 gf(250, B_N);               // 4 frames/block
  k_fft<<<gf, blk, 0, stream>>>(Pb, z, twTab, winTab, out, sbl, sbr);
  k_even<<<2000, blk, 0, stream>>>(sbl, sbr, out);
}